// Round 11
// baseline (486.277 us; speedup 1.0000x reference)
//
#include <hip/hip_runtime.h>
#include <hip/hip_bf16.h>

#define BATCH 16384
#define HDIM  1024
#define K1    2048
#define N1    4096

typedef __attribute__((ext_vector_type(4))) float f32x4;
typedef __attribute__((ext_vector_type(8))) short short8;

__device__ __forceinline__ unsigned short f2bf(float f) {
  union { float f; unsigned u; } v; v.f = f;
  unsigned r = v.u + 0x7FFFu + ((v.u >> 16) & 1u);
  return (unsigned short)(r >> 16);
}
__device__ __forceinline__ float bf2f(unsigned short h) {
  union { unsigned u; float f; } v; v.u = ((unsigned)h) << 16; return v.f;
}
__device__ __forceinline__ float sigmoidf_(float x) {
  return 1.0f / (1.0f + __builtin_amdgcn_exp2f(x * -1.4426950408889634f));
}
__device__ __forceinline__ float tanhf_(float x) {
  float xc = fminf(fmaxf(x, -8.0f), 8.0f);
  float e = __builtin_amdgcn_exp2f(xc * 2.8853900817779268f);
  return (e - 1.0f) / (e + 1.0f);
}
__device__ __forceinline__ void async16(const void* g, void* l) {
  __builtin_amdgcn_global_load_lds((const __attribute__((address_space(1))) void*)g,
                                   (__attribute__((address_space(3))) void*)l, 16, 0, 0);
}

// ---- conversion pass: U = [x|y] bf16 (16384 x 2048) ----
__global__ void k_convU(const float* __restrict__ x, const float* __restrict__ y,
                        unsigned short* __restrict__ U) {
  const int total = BATCH * (HDIM / 4);
  for (int q = blockIdx.x * blockDim.x + threadIdx.x; q < total;
       q += gridDim.x * blockDim.x) {
    int b = q >> 8;
    int c = (q & 255) << 2;
    float4 xv = *(const float4*)(x + (long)b * HDIM + c);
    float4 yv = *(const float4*)(y + (long)b * HDIM + c);
    uint2 xo, yo;
    xo.x = (unsigned)f2bf(xv.x) | ((unsigned)f2bf(xv.y) << 16);
    xo.y = (unsigned)f2bf(xv.z) | ((unsigned)f2bf(xv.w) << 16);
    yo.x = (unsigned)f2bf(yv.x) | ((unsigned)f2bf(yv.y) << 16);
    yo.y = (unsigned)f2bf(yv.z) | ((unsigned)f2bf(yv.w) << 16);
    *(uint2*)(U + (long)b * K1 + c) = xo;
    *(uint2*)(U + (long)b * K1 + HDIM + c) = yo;
  }
}

// ---- conversion: permuted 4-chunk Wcat (4096 x 2048) + Wzb (1024 x 1024) ----
// n' = B*256 + w*64 + c*16 + i  -> chunk c of h = B*64 + w*16 + i
//   c0: [W_ih[h]    | W_hh[h]   ]   c1: [W_ih[H+h] | W_hh[H+h]]
//   c2: [W_ih[3H+h] | W_hh[2H+h]]   c3: [W_ih[2H+h]| 0        ]  (i_z)
__global__ void k_convW(const float* __restrict__ Wih, const float* __restrict__ Whh,
                        const float* __restrict__ Wz,
                        unsigned short* __restrict__ Wcat, unsigned short* __restrict__ Wzb) {
  const int stride = gridDim.x * blockDim.x;
  const int totalW = N1 * (K1 / 4);
  for (int q = blockIdx.x * blockDim.x + threadIdx.x; q < totalW; q += stride) {
    int np = q >> 9;
    int kb = (q & 511) << 2;
    int B = np >> 8, w = (np >> 6) & 3, c = (np >> 4) & 3, i = np & 15;
    int h = B * 64 + w * 16 + i;
    float4 v;
    if (kb < HDIM) {
      int row = (c == 0) ? h : (c == 1) ? (HDIM + h) : (c == 2) ? (3 * HDIM + h) : (2 * HDIM + h);
      v = *(const float4*)(Wih + (long)row * HDIM + kb);
    } else if (c == 3) {
      v = make_float4(0.f, 0.f, 0.f, 0.f);
    } else {
      int row = (c == 0) ? h : (c == 1) ? (HDIM + h) : (2 * HDIM + h);
      v = *(const float4*)(Whh + (long)row * HDIM + (kb - HDIM));
    }
    uint2 o;
    o.x = (unsigned)f2bf(v.x) | ((unsigned)f2bf(v.y) << 16);
    o.y = (unsigned)f2bf(v.z) | ((unsigned)f2bf(v.w) << 16);
    *(uint2*)(Wcat + (long)np * K1 + kb) = o;
  }
  const int totalZ = HDIM * (HDIM / 4);
  for (int q = blockIdx.x * blockDim.x + threadIdx.x; q < totalZ; q += stride) {
    int n = q >> 8;
    int kb = (q & 255) << 2;
    float4 v = *(const float4*)(Wz + (long)n * HDIM + kb);
    uint2 o;
    o.x = (unsigned)f2bf(v.x) | ((unsigned)f2bf(v.y) << 16);
    o.y = (unsigned)f2bf(v.z) | ((unsigned)f2bf(v.w) << 16);
    *(uint2*)(Wzb + (long)n * HDIM + kb) = o;
  }
}

// ---- m201 8-phase 256x256 GEMM core (faithful port) ----
// 8 waves (2M x 4N), per-wave 128x64. BK=64 K-tiles, 2 LDS dbuf (tile&1),
// LDS 128KB = {A,B} x 2buf x 2half x (128 x 64 x 2B). 8 phases per iter
// (2 K-tiles). Phase = {subtile ds_reads (0/4/8/12 b128); stage ONE
// half-tile (2 global_load_lds); [lgkmcnt(8) if 12 reads]; [vmcnt(2) at
// phases 4/8 only]; barrier; lgkmcnt(0); setprio(1); 16 MFMA; setprio(0);
// barrier}. Stage slot for tile T half h = phase 4T-5+h: provably after
// tile T-2's reads drained (its P2 barrier pair), landed before tile T's
// reads via the boundary vmcnt(2). Zero-conflict swizzle: phys byte =
// L ^ ((row&7)<<4) (stride-128B rows), staged via pre-swizzled source.
template <int NT>
__device__ __forceinline__ void gemm8p(
    const unsigned short* __restrict__ A, int strA,
    const unsigned short* __restrict__ Bm, int strB,
    long arow0, long brow0, char* ldsA, char* ldsB, f32x4 acc[8][4]) {
  constexpr int NITER = NT / 2;
  const int t = threadIdx.x, lane = t & 63, wv = t >> 6;
  const int wm = wv >> 2, wn = wv & 3;
  const int rA = lane & 15, kg = lane >> 4;
  const int xsw = (rA & 7) << 4;

  int offA[2][4][2], offB[2][2][2];
#pragma unroll
  for (int mh = 0; mh < 2; ++mh)
#pragma unroll
    for (int mq = 0; mq < 4; ++mq)
#pragma unroll
      for (int ks = 0; ks < 2; ++ks) {
        int rr = mh * 64 + mq * 16 + rA;
        offA[mh][mq][ks] = wm * 16384 + rr * 128 + ((ks * 64 + kg * 16) ^ xsw);
      }
#pragma unroll
  for (int nh = 0; nh < 2; ++nh)
#pragma unroll
    for (int nq = 0; nq < 2; ++nq)
#pragma unroll
      for (int ks = 0; ks < 2; ++ks) {
        int rb = (wn & 1) * 64 + nh * 32 + nq * 16 + rA;
        offB[nh][nq][ks] = (wn >> 1) * 16384 + rb * 128 + ((ks * 64 + kg * 16) ^ xsw);
      }

  const int t16 = t * 16;
  const int L0 = t16 ^ (((t16 >> 7) & 7) << 4);
  const int r0 = L0 >> 7, c0 = (L0 & 127) >> 1;
  const unsigned short* pA = A + (arow0 + r0) * (long)strA + c0;
  const unsigned short* pB = Bm + (brow0 + r0) * (long)strB + c0;

#define SHALF_(TH, hh)                                                          \
  do {                                                                          \
    if ((hh) < 2) {                                                             \
      char* db_ = ldsA + ((TH) & 1) * 32768 + (hh) * 16384;                     \
      const unsigned short* sp_ = pA + ((long)(hh) * 128) * strA + (long)(TH) * 64; \
      async16(sp_, db_ + t16);                                                  \
      async16(sp_ + (long)64 * strA, db_ + 8192 + t16);                         \
    } else {                                                                    \
      char* db_ = ldsB + ((TH) & 1) * 32768 + ((hh) - 2) * 16384;               \
      const unsigned short* sp_ = pB + ((long)((hh) - 2) * 128) * strB + (long)(TH) * 64; \
      async16(sp_, db_ + t16);                                                  \
      async16(sp_ + (long)64 * strB, db_ + 8192 + t16);                         \
    }                                                                           \
  } while (0)
#define STG_(H)                                                                 \
  do { int H_ = (H); if (H_ >= 8 && H_ < 4 * NT) SHALF_(H_ >> 2, H_ & 3); } while (0)

#define PHASE_(D, MH, NH, RD, BF, H, VMN, LG8)                                  \
  do {                                                                          \
    const char* Ab_ = ldsA + (D) * 32768;                                       \
    const char* Bb_ = ldsB + (D) * 32768;                                       \
    if ((RD) == 0 || (RD) == 2) {                                               \
      _Pragma("unroll") for (int mq = 0; mq < 4; ++mq)                          \
        _Pragma("unroll") for (int ks = 0; ks < 2; ++ks)                        \
          aF[mq][ks] = *(const short8*)(Ab_ + offA[MH][mq][ks]);                \
    }                                                                           \
    if ((RD) == 0 || (RD) == 1) {                                               \
      _Pragma("unroll") for (int nq = 0; nq < 2; ++nq)                          \
        _Pragma("unroll") for (int ks = 0; ks < 2; ++ks)                        \
          BF[nq][ks] = *(const short8*)(Bb_ + offB[NH][nq][ks]);                \
    }                                                                           \
    STG_(H);                                                                    \
    if (LG8) asm volatile("s_waitcnt lgkmcnt(8)" ::: "memory");                 \
    if ((VMN) == 2) asm volatile("s_waitcnt vmcnt(2)" ::: "memory");            \
    if ((VMN) == 0) asm volatile("s_waitcnt vmcnt(0)" ::: "memory");            \
    __builtin_amdgcn_sched_barrier(0);                                          \
    __builtin_amdgcn_s_barrier();                                               \
    asm volatile("s_waitcnt lgkmcnt(0)" ::: "memory");                          \
    __builtin_amdgcn_sched_barrier(0);                                          \
    __builtin_amdgcn_s_setprio(1);                                              \
    _Pragma("unroll") for (int mq = 0; mq < 4; ++mq)                            \
      _Pragma("unroll") for (int nq = 0; nq < 2; ++nq)                          \
        _Pragma("unroll") for (int ks = 0; ks < 2; ++ks)                        \
          acc[(MH) * 4 + mq][(NH) * 2 + nq] =                                   \
              __builtin_amdgcn_mfma_f32_16x16x32_bf16(                          \
                  aF[mq][ks], BF[nq][ks], acc[(MH) * 4 + mq][(NH) * 2 + nq], 0, 0, 0); \
    __builtin_amdgcn_s_setprio(0);                                              \
    __builtin_amdgcn_s_barrier();                                               \
  } while (0)

  short8 aF[4][2], bF0[2][2], bF1[2][2];
  // prologue: stage tiles 0 and 1 (8 half-tiles, 16 loads)
#pragma unroll
  for (int H = 0; H < 8; ++H) SHALF_(H >> 2, H & 3);
  asm volatile("s_waitcnt vmcnt(8)" ::: "memory");  // tile 0 landed
  __builtin_amdgcn_sched_barrier(0);
  __builtin_amdgcn_s_barrier();

#pragma unroll 1
  for (int it = 0; it < NITER; ++it) {
    const int H0 = it * 8 + 5;
    PHASE_(0, 0, 0, 0, bF0, H0 + 0, -1, 1);
    PHASE_(0, 0, 1, 1, bF1, H0 + 1, -1, 0);
    PHASE_(0, 1, 0, 2, bF0, H0 + 2, -1, 0);
    if (it < NITER - 1) PHASE_(0, 1, 1, 3, bF1, H0 + 3, 2, 0);
    else                PHASE_(0, 1, 1, 3, bF1, H0 + 3, 0, 0);
    PHASE_(1, 0, 0, 0, bF0, H0 + 4, -1, 1);
    PHASE_(1, 0, 1, 1, bF1, H0 + 5, -1, 0);
    PHASE_(1, 1, 0, 2, bF0, H0 + 6, -1, 0);
    if (it < NITER - 1) PHASE_(1, 1, 1, 3, bF1, H0 + 7, 2, 0);
    else                PHASE_(1, 1, 1, 3, bF1, H0 + 7, -1, 0);
  }
#undef SHALF_
#undef STG_
#undef PHASE_
}

// ---- phase 1: fused U@Wcat^T + LEM elementwise (256x256 tiles) ----
__global__ __launch_bounds__(512, 2) void k_gemm1(
    const unsigned short* __restrict__ U, const unsigned short* __restrict__ Wcat,
    const float* __restrict__ z, const float* __restrict__ dtp,
    const float* __restrict__ bih, const float* __restrict__ bhh,
    const float* __restrict__ Wdt, const float* __restrict__ bdt,
    float* __restrict__ out, unsigned short* __restrict__ znb,
    unsigned short* __restrict__ sbb) {
  __shared__ char lds[131072];
  char* ldsA = lds;
  char* ldsB = lds + 65536;
  const int bid = blockIdx.x;
  const int sid = (bid & 7) * 128 + (bid >> 3);  // XCD-bijective (1024 % 8 == 0)
  const int bm = sid >> 4, bn = sid & 15;
  f32x4 acc[8][4];
#pragma unroll
  for (int m = 0; m < 8; ++m)
#pragma unroll
    for (int n = 0; n < 4; ++n) acc[m][n] = (f32x4)(0.0f);

  gemm8p<32>(U, K1, Wcat, K1, (long)bm * 256, (long)bn * 256, ldsA, ldsB, acc);

  const int t = threadIdx.x, lane = t & 63, wv = t >> 6;
  const int wm = wv >> 2, wn = wv & 3;
  const int rA = lane & 15, q4 = (lane >> 4) << 2;
  const int h = bn * 64 + wn * 16 + rA;
  const int rowbase = bm * 256 + wm * 128;
  const float bi0 = bih[h] + bhh[h];
  const float bi1 = bih[HDIM + h] + bhh[HDIM + h];
  const float bi2 = bih[3 * HDIM + h] + bhh[2 * HDIM + h];
  const float bi3 = bih[2 * HDIM + h];
  const float wdt0 = Wdt[0], wdt1 = Wdt[1], bdt0 = bdt[0], bdt1 = bdt[1];
#pragma unroll
  for (int r = 0; r < 8; ++r) {
    const int rowblk = (r >> 2) * 64 + (r & 3) * 16;
#pragma unroll
    for (int j = 0; j < 4; ++j) {
      const int b = rowbase + rowblk + q4 + j;
      const long idx = (long)b * HDIM + h;
      const float dv = dtp[b];
      const float s1 = sigmoidf_(dv * wdt0 + bdt0);
      const float s2 = sigmoidf_(dv * wdt1 + bdt1);
      const float sbar = s1 * sigmoidf_(acc[r][0][j] + bi0);
      const float s = s2 * sigmoidf_(acc[r][1][j] + bi1);
      const float zt = tanhf_(acc[r][2][j] + bi2);
      const float iz = acc[r][3][j] + bi3;
      const float znew = (1.0f - s) * z[idx] + s * zt;
      out[(long)BATCH * HDIM + idx] = znew;  // z_new output (f32)
      out[idx] = iz;                          // park i_z in y_new slot
      znb[idx] = f2bf(znew);                  // bf16 operand for phase 2
      sbb[idx] = f2bf(sbar);
    }
  }
}

// ---- phase 2: z_new@Wz^T + y_new epilogue (256x256 tiles, K=1024) ----
__global__ __launch_bounds__(512, 2) void k_gemm2(
    const unsigned short* __restrict__ Zn, const unsigned short* __restrict__ Wzb,
    const unsigned short* __restrict__ sbb, const float* __restrict__ yin,
    const float* __restrict__ bz, float* __restrict__ out) {
  __shared__ char lds[131072];
  char* ldsA = lds;
  char* ldsB = lds + 65536;
  const int bid = blockIdx.x;
  const int sid = (bid & 7) * 32 + (bid >> 3);  // 256 % 8 == 0
  const int bm = sid >> 2, bn = sid & 3;
  f32x4 acc[8][4];
#pragma unroll
  for (int m = 0; m < 8; ++m)
#pragma unroll
    for (int n = 0; n < 4; ++n) acc[m][n] = (f32x4)(0.0f);

  gemm8p<16>(Zn, HDIM, Wzb, HDIM, (long)bm * 256, (long)bn * 256, ldsA, ldsB, acc);

  const int t = threadIdx.x, lane = t & 63, wv = t >> 6;
  const int wm = wv >> 2, wn = wv & 3;
  const int rA = lane & 15, q4 = (lane >> 4) << 2;
  const int rowbase = bm * 256 + wm * 128;
#pragma unroll
  for (int n = 0; n < 4; ++n) {
    const int hc = bn * 256 + wn * 64 + n * 16 + rA;
    const float bzv = bz[hc];
#pragma unroll
    for (int r = 0; r < 8; ++r) {
      const int rowblk = (r >> 2) * 64 + (r & 3) * 16;
#pragma unroll
      for (int j = 0; j < 4; ++j) {
        const int b = rowbase + rowblk + q4 + j;
        const long idx = (long)b * HDIM + hc;
        const float tv = tanhf_(acc[r][n][j] + bzv + out[idx]);  // out[idx] holds i_z
        const float sb = bf2f(sbb[idx]);
        out[idx] = (1.0f - sb) * yin[idx] + sb * tv;  // y_new (same addr, same thread)
      }
    }
  }
}

extern "C" void kernel_launch(void* const* d_in, const int* in_sizes, int n_in,
                              void* d_out, int out_size, void* d_ws, size_t ws_size,
                              hipStream_t stream) {
  const float* x   = (const float*)d_in[0];
  const float* y   = (const float*)d_in[1];
  const float* z   = (const float*)d_in[2];
  const float* dtp = (const float*)d_in[3];
  const float* Wih = (const float*)d_in[4];
  const float* bih = (const float*)d_in[5];
  const float* Whh = (const float*)d_in[6];
  const float* bhh = (const float*)d_in[7];
  const float* Wz  = (const float*)d_in[8];
  const float* bz  = (const float*)d_in[9];
  const float* Wdt = (const float*)d_in[10];
  const float* bdt = (const float*)d_in[11];

  char* ws = (char*)d_ws;
  unsigned short* U    = (unsigned short*)(ws);              // 67,108,864 B
  unsigned short* Wcat = (unsigned short*)(ws + 67108864);   // 16,777,216 B
  unsigned short* Wzb  = (unsigned short*)(ws + 83886080);   //  2,097,152 B
  unsigned short* Znb  = (unsigned short*)(ws + 85983232);   // 33,554,432 B
  unsigned short* Sbb  = (unsigned short*)(ws + 119537664);  // 33,554,432 B
  float* out = (float*)d_out;

  k_convU<<<2048, 256, 0, stream>>>(x, y, U);
  k_convW<<<2048, 256, 0, stream>>>(Wih, Whh, Wz, Wcat, Wzb);
  k_gemm1<<<1024, 512, 0, stream>>>(U, Wcat, z, dtp, bih, bhh, Wdt, bdt, out, Znb, Sbb);
  k_gemm2<<<256, 512, 0, stream>>>(Znb, Wzb, Sbb, y, bz, out);
}

// Round 12
// 391.875 us; speedup vs baseline: 1.2409x; 1.2409x over previous
//
#include <hip/hip_runtime.h>
#include <hip/hip_bf16.h>

#define BATCH 16384
#define HDIM  1024
#define K1    2048

typedef __attribute__((ext_vector_type(4))) float f32x4;
typedef __attribute__((ext_vector_type(8))) short short8;

__device__ __forceinline__ unsigned short f2bf(float f) {
  union { float f; unsigned u; } v; v.f = f;
  unsigned r = v.u + 0x7FFFu + ((v.u >> 16) & 1u);
  return (unsigned short)(r >> 16);
}
__device__ __forceinline__ float bf2f(unsigned short h) {
  union { unsigned u; float f; } v; v.u = ((unsigned)h) << 16; return v.f;
}
__device__ __forceinline__ float sigmoidf_(float x) {
  return 1.0f / (1.0f + __builtin_amdgcn_exp2f(x * -1.4426950408889634f));
}
__device__ __forceinline__ float tanhf_(float x) {
  float xc = fminf(fmaxf(x, -8.0f), 8.0f);
  float e = __builtin_amdgcn_exp2f(xc * 2.8853900817779268f);
  return (e - 1.0f) / (e + 1.0f);
}
__device__ __forceinline__ void async16(const void* g, void* l) {
  __builtin_amdgcn_global_load_lds((const __attribute__((address_space(1))) void*)g,
                                   (__attribute__((address_space(3))) void*)l, 16, 0, 0);
}

// ---- merged conversion pass: U, permuted Wcat (3072 x 2048), Wzcat ----
// Wcat n' = bn*192 + w*48 + c*16 + i -> chunk c of h = bn*64 + w*16 + i
// Wzcat row n = [Wz[n] | W_ih[2H+n]]  (z_new@Wz^T + i_z fused, K=2048)
__global__ void k_conv(const float* __restrict__ x, const float* __restrict__ y,
                       const float* __restrict__ Wih, const float* __restrict__ Whh,
                       const float* __restrict__ Wz,
                       unsigned short* __restrict__ U,
                       unsigned short* __restrict__ Wcat,
                       unsigned short* __restrict__ Wzcat) {
  const int stride = gridDim.x * blockDim.x;
  const int tid0 = blockIdx.x * blockDim.x + threadIdx.x;
  const int totalU = BATCH * (HDIM / 4);
  for (int q = tid0; q < totalU; q += stride) {
    int b = q >> 8;
    int c = (q & 255) << 2;
    float4 xv = *(const float4*)(x + (long)b * HDIM + c);
    float4 yv = *(const float4*)(y + (long)b * HDIM + c);
    uint2 xo, yo;
    xo.x = (unsigned)f2bf(xv.x) | ((unsigned)f2bf(xv.y) << 16);
    xo.y = (unsigned)f2bf(xv.z) | ((unsigned)f2bf(xv.w) << 16);
    yo.x = (unsigned)f2bf(yv.x) | ((unsigned)f2bf(yv.y) << 16);
    yo.y = (unsigned)f2bf(yv.z) | ((unsigned)f2bf(yv.w) << 16);
    *(uint2*)(U + (long)b * K1 + c) = xo;
    *(uint2*)(U + (long)b * K1 + HDIM + c) = yo;
  }
  const int totalW = 3072 * (K1 / 4);
  for (int q = tid0; q < totalW; q += stride) {
    int np = q >> 9;
    int kb = (q & 511) << 2;
    int bn = np / 192; int r = np - bn * 192;
    int w = r / 48; int r2 = r - w * 48;
    int c = r2 >> 4, i = r2 & 15;
    int h = bn * 64 + w * 16 + i;
    float4 v;
    if (kb < HDIM) {
      int row = (c == 0) ? h : (c == 1) ? (HDIM + h) : (3 * HDIM + h);
      v = *(const float4*)(Wih + (long)row * HDIM + kb);
    } else {
      int row = (c == 0) ? h : (c == 1) ? (HDIM + h) : (2 * HDIM + h);
      v = *(const float4*)(Whh + (long)row * HDIM + (kb - HDIM));
    }
    uint2 o;
    o.x = (unsigned)f2bf(v.x) | ((unsigned)f2bf(v.y) << 16);
    o.y = (unsigned)f2bf(v.z) | ((unsigned)f2bf(v.w) << 16);
    *(uint2*)(Wcat + (long)np * K1 + kb) = o;
  }
  const int totalZ = HDIM * (K1 / 4);
  for (int q = tid0; q < totalZ; q += stride) {
    int n = q >> 9;
    int kb = (q & 511) << 2;
    float4 v = (kb < HDIM) ? *(const float4*)(Wz + (long)n * HDIM + kb)
                           : *(const float4*)(Wih + (long)(2 * HDIM + n) * HDIM + (kb - HDIM));
    uint2 o;
    o.x = (unsigned)f2bf(v.x) | ((unsigned)f2bf(v.y) << 16);
    o.y = (unsigned)f2bf(v.z) | ((unsigned)f2bf(v.w) << 16);
    *(uint2*)(Wzcat + (long)n * K1 + kb) = o;
  }
}

// ---- GEMM core v2: 256 x (NB*64) tile, 8 waves, 5-buffer ring ----
// BK=32 K-tiles. 5 LDS buffers, stage distance 3 (ring: stage at iter kt
// targets (kt+3)%5 = (kt-2)%5, whose reads were consumed before
// barrier(kt-1); overwrite issues after barrier(kt-1) -> barrier alone is
// the overwrite fence). NO manual lgkmcnt(0) and NO sched_barrier on the
// critical path: compiler's per-use lgkmcnt lands after the barrier, so
// ds_read latency hides under barrier skew + MFMA. Read-readiness: counted
// vmcnt leaves newest 2 stages in flight, forcing stage(kt+1) complete
// before barrier(kt); reads(kt+1) execute after barrier(kt).
// Per kt: {8+NB ds_read; stage(kt+3); vmcnt(counted); s_barrier;
//          setprio(1); 8*NB MFMA; setprio(0)}.
// LDS XOR-swizzle (64B rows, slot = rA&7 form) via pre-swizzled global
// source; 0 bank conflicts (PMC-verified R3-R11).
template <int NB, int KSPLIT, bool BSPLIT>
__device__ __forceinline__ void gemm_core(
    const unsigned short* __restrict__ A1, int strA1,
    const unsigned short* __restrict__ A2, int strA2,
    const unsigned short* __restrict__ Bg,
    long arow0, long brow0, char* lds, f32x4 acc[8][NB]) {
  constexpr int NT = 64;
  constexpr int ABY = 16384;
  constexpr int BBY = NB * 4096;
  char* ldsA = lds;              // 5 x 16KB
  char* ldsB = lds + 5 * ABY;    // 5 x BBY
  const int t = threadIdx.x, lane = t & 63, wv = t >> 6;
  const int wm = wv >> 2, wn = wv & 3;
  const int rA = lane & 15;
  const int cphys = ((lane >> 4) << 4) ^ (((rA >> 1) & 3) << 4);
  const int t16 = t * 16;
  const bool blo = (t < 256);

  // A staging (16KB tile = 2 loads/thread), inverse-swizzled source
  const int sA = t16 ^ (((t16 >> 7) & 3) << 4);
  const int rA0 = sA >> 6, cA0 = (sA & 63) >> 1;
  const unsigned short* pA1a = A1 + (arow0 + rA0) * (long)strA1 + cA0;
  const unsigned short* pA1b = A1 + (arow0 + rA0 + 128) * (long)strA1 + cA0;
  const unsigned short* pA2a = A2 + (arow0 + rA0) * (long)strA2 + cA0;
  const unsigned short* pA2b = A2 + (arow0 + rA0 + 128) * (long)strA2 + cA0;

  // B staging: BSPLIT (12KB): lo waves 2 loads (L=t16, t16+4096), hi 1
  // (L=t16+4096). !BSPLIT (8KB): 1 load (L=t16).
  const int Lb0 = BSPLIT ? (blo ? t16 : t16 + 4096) : t16;
  const int Lb1 = t16 + 4096;
  const int sB0 = Lb0 ^ (((Lb0 >> 7) & 3) << 4);
  const int sB1 = Lb1 ^ (((Lb1 >> 7) & 3) << 4);
  const unsigned short* pBg0 = Bg + (brow0 + (sB0 >> 6)) * (long)K1 + ((sB0 & 63) >> 1);
  const unsigned short* pBg1 = Bg + (brow0 + (sB1 >> 6)) * (long)K1 + ((sB1 & 63) >> 1);

  int offA[8], offB[NB];
#pragma unroll
  for (int m = 0; m < 8; ++m)
    offA[m] = (wm * 128 + m * 16 + rA) * 64 + cphys;
#pragma unroll
  for (int n = 0; n < NB; ++n)
    offB[n] = (wn * (NB * 16) + n * 16 + rA) * 64 + cphys;

#define STAGE_TO_(AB_, BB_, TT)                                           \
  do {                                                                    \
    if ((TT) < KSPLIT) {                                                  \
      async16(pA1a + (long)(TT) * 32, (AB_) + t16);                       \
      async16(pA1b + (long)(TT) * 32, (AB_) + 8192 + t16);                \
    } else {                                                              \
      async16(pA2a + (long)((TT) - KSPLIT) * 32, (AB_) + t16);            \
      async16(pA2b + (long)((TT) - KSPLIT) * 32, (AB_) + 8192 + t16);     \
    }                                                                     \
    async16(pBg0 + (long)(TT) * 32, (BB_) + Lb0);                         \
    if (BSPLIT && blo) async16(pBg1 + (long)(TT) * 32, (BB_) + Lb1);      \
  } while (0)
#define VM_STEADY_                                                        \
  do {                                                                    \
    if (BSPLIT) {                                                         \
      if (blo) asm volatile("s_waitcnt vmcnt(8)" ::: "memory");           \
      else     asm volatile("s_waitcnt vmcnt(6)" ::: "memory");           \
    } else     asm volatile("s_waitcnt vmcnt(6)" ::: "memory");           \
  } while (0)
#define VM_TAIL1_                                                         \
  do {                                                                    \
    if (BSPLIT) {                                                         \
      if (blo) asm volatile("s_waitcnt vmcnt(4)" ::: "memory");           \
      else     asm volatile("s_waitcnt vmcnt(3)" ::: "memory");           \
    } else     asm volatile("s_waitcnt vmcnt(3)" ::: "memory");           \
  } while (0)
#define VM_TAIL0_ asm volatile("s_waitcnt vmcnt(0)" ::: "memory")

  // prologue: stage K-tiles 0,1,2 into buffers 0,1,2; ensure tile 0 landed
  STAGE_TO_(ldsA, ldsB, 0);
  STAGE_TO_(ldsA + ABY, ldsB + BBY, 1);
  STAGE_TO_(ldsA + 2 * ABY, ldsB + 2 * BBY, 2);
  VM_STEADY_;
  __builtin_amdgcn_s_barrier();

  // rotating ring pointers: read buffer kt%5, stage buffer (kt+3)%5
  const char* rdA = ldsA;
  const char* rdB = ldsB;
  char* stA = ldsA + 3 * ABY;
  char* stB = ldsB + 3 * BBY;
  const char* ldsAend = ldsA + 5 * ABY;
  const char* ldsBend = ldsB + 5 * BBY;

#pragma unroll 1
  for (int kt = 0; kt < NT; ++kt) {
    short8 af_[8], bf_[NB];
#pragma unroll
    for (int m = 0; m < 8; ++m) af_[m] = *(const short8*)(rdA + offA[m]);
#pragma unroll
    for (int n = 0; n < NB; ++n) bf_[n] = *(const short8*)(rdB + offB[n]);
    if (kt < NT - 3) {
      STAGE_TO_(stA, stB, kt + 3);
      VM_STEADY_;
    } else if (kt == NT - 3) {
      VM_TAIL1_;
    } else if (kt == NT - 2) {
      VM_TAIL0_;
    }
    __builtin_amdgcn_s_barrier();
    __builtin_amdgcn_s_setprio(1);
#pragma unroll
    for (int m = 0; m < 8; ++m)
#pragma unroll
      for (int n = 0; n < NB; ++n)
        acc[m][n] = __builtin_amdgcn_mfma_f32_16x16x32_bf16(
            af_[m], bf_[n], acc[m][n], 0, 0, 0);
    __builtin_amdgcn_s_setprio(0);
    rdA += ABY; rdA = (rdA == ldsAend) ? ldsA : rdA;
    rdB += BBY; rdB = (rdB == ldsBend) ? ldsB : rdB;
    stA += ABY; stA = (stA == ldsAend) ? (char*)ldsA : stA;
    stB += BBY; stB = (stB == ldsBend) ? (char*)ldsB : stB;
  }
#undef STAGE_TO_
#undef VM_STEADY_
#undef VM_TAIL1_
#undef VM_TAIL0_
}

// ---- phase 1: fused U@Wcat^T + LEM elementwise (256x192 tiles) ----
__global__ __launch_bounds__(512, 2) void k_gemm1(
    const unsigned short* __restrict__ U, const unsigned short* __restrict__ Wcat,
    const float* __restrict__ z, const float* __restrict__ dtp,
    const float* __restrict__ bih, const float* __restrict__ bhh,
    const float* __restrict__ Wdt, const float* __restrict__ bdt,
    float* __restrict__ out, unsigned short* __restrict__ znb,
    unsigned short* __restrict__ sbb) {
  __shared__ char lds[143360];  // 5x16KB A + 5x12KB B
  const int bid = blockIdx.x;
  const int sid = (bid & 7) * 128 + (bid >> 3);  // XCD-bijective (1024 % 8 == 0)
  const int bm = sid >> 4, bn = sid & 15;
  f32x4 acc[8][3];
#pragma unroll
  for (int m = 0; m < 8; ++m)
#pragma unroll
    for (int n = 0; n < 3; ++n) acc[m][n] = (f32x4)(0.0f);

  gemm_core<3, 64, true>(U, K1, U, K1, Wcat, (long)bm * 256, (long)bn * 192, lds, acc);

  const int t = threadIdx.x, lane = t & 63, wv = t >> 6;
  const int wm = wv >> 2, wn = wv & 3;
  const int rA = lane & 15, q4 = (lane >> 4) << 2;
  const int h = bn * 64 + wn * 16 + rA;
  const int rowbase = bm * 256 + wm * 128;
  const float bi0 = bih[h] + bhh[h];
  const float bi1 = bih[HDIM + h] + bhh[HDIM + h];
  const float bi2 = bih[3 * HDIM + h] + bhh[2 * HDIM + h];
  const float wdt0 = Wdt[0], wdt1 = Wdt[1], bdt0 = bdt[0], bdt1 = bdt[1];
#pragma unroll
  for (int m = 0; m < 8; ++m) {
#pragma unroll
    for (int j = 0; j < 4; ++j) {
      const int b = rowbase + m * 16 + q4 + j;
      const long idx = (long)b * HDIM + h;
      const float dv = dtp[b];
      const float s1 = sigmoidf_(dv * wdt0 + bdt0);
      const float s2 = sigmoidf_(dv * wdt1 + bdt1);
      const float sbar = s1 * sigmoidf_(acc[m][0][j] + bi0);
      const float s = s2 * sigmoidf_(acc[m][1][j] + bi1);
      const float zt = tanhf_(acc[m][2][j] + bi2);
      const float znew = (1.0f - s) * z[idx] + s * zt;
      out[(long)BATCH * HDIM + idx] = znew;  // z_new output (f32)
      znb[idx] = f2bf(znew);                  // A-left-half for phase 2
      sbb[idx] = f2bf(sbar);
    }
  }
}

// ---- phase 2: [z_new|x]@[Wz|Wih_2H]^T + y_new epilogue (256x128 tiles) ----
__global__ __launch_bounds__(512, 2) void k_gemm2(
    const unsigned short* __restrict__ Zn, const unsigned short* __restrict__ U,
    const unsigned short* __restrict__ Wzcat, const unsigned short* __restrict__ sbb,
    const float* __restrict__ yin, const float* __restrict__ bz,
    float* __restrict__ out) {
  __shared__ char lds[122880];  // 5x16KB A + 5x8KB B
  const int bid = blockIdx.x;
  const int sid = (bid & 7) * 64 + (bid >> 3);  // 512 % 8 == 0
  const int bm = sid >> 3, bn = sid & 7;
  f32x4 acc[8][2];
#pragma unroll
  for (int m = 0; m < 8; ++m)
#pragma unroll
    for (int n = 0; n < 2; ++n) acc[m][n] = (f32x4)(0.0f);

  // A: kt<32 -> Znb (stride 1024), kt>=32 -> x half of U (stride 2048)
  gemm_core<2, 32, false>(Zn, HDIM, U, K1, Wzcat, (long)bm * 256, (long)bn * 128, lds, acc);

  const int t = threadIdx.x, lane = t & 63, wv = t >> 6;
  const int wm = wv >> 2, wn = wv & 3;
  const int rA = lane & 15, q4 = (lane >> 4) << 2;
  const int rowbase = bm * 256 + wm * 128;
#pragma unroll
  for (int n = 0; n < 2; ++n) {
    const int hc = bn * 128 + wn * 32 + n * 16 + rA;
    const float bzv = bz[hc];
#pragma unroll
    for (int m = 0; m < 8; ++m) {
#pragma unroll
      for (int j = 0; j < 4; ++j) {
        const int b = rowbase + m * 16 + q4 + j;
        const long idx = (long)b * HDIM + hc;
        const float tv = tanhf_(acc[m][n][j] + bzv);
        const float sb = bf2f(sbb[idx]);
        out[idx] = (1.0f - sb) * yin[idx] + sb * tv;  // y_new
      }
    }
  }
}

extern "C" void kernel_launch(void* const* d_in, const int* in_sizes, int n_in,
                              void* d_out, int out_size, void* d_ws, size_t ws_size,
                              hipStream_t stream) {
  const float* x   = (const float*)d_in[0];
  const float* y   = (const float*)d_in[1];
  const float* z   = (const float*)d_in[2];
  const float* dtp = (const float*)d_in[3];
  const float* Wih = (const float*)d_in[4];
  const float* bih = (const float*)d_in[5];
  const float* Whh = (const float*)d_in[6];
  const float* bhh = (const float*)d_in[7];
  const float* Wz  = (const float*)d_in[8];
  const float* bz  = (const float*)d_in[9];
  const float* Wdt = (const float*)d_in[10];
  const float* bdt = (const float*)d_in[11];

  char* ws = (char*)d_ws;
  unsigned short* U     = (unsigned short*)(ws);              // 67,108,864 B
  unsigned short* Wcat  = (unsigned short*)(ws + 67108864);   // 12,582,912 B
  unsigned short* Wzcat = (unsigned short*)(ws + 79691776);   //  4,194,304 B
  unsigned short* Znb   = (unsigned short*)(ws + 83886080);   // 33,554,432 B
  unsigned short* Sbb   = (unsigned short*)(ws + 117440512);  // 33,554,432 B -> 150,994,944 B
  float* out = (float*)d_out;

  k_conv<<<2048, 256, 0, stream>>>(x, y, Wih, Whh, Wz, U, Wcat, Wzcat);
  k_gemm1<<<1024, 512, 0, stream>>>(U, Wcat, z, dtp, bih, bhh, Wdt, bdt, out, Znb, Sbb);
  k_gemm2<<<512, 512, 0, stream>>>(Znb, U, Wzcat, Sbb, y, bz, out);
}

// Round 14
// 382.569 us; speedup vs baseline: 1.2711x; 1.0243x over previous
//
#include <hip/hip_runtime.h>
#include <hip/hip_bf16.h>

#define BATCH 16384
#define HDIM  1024
#define K1    2048

typedef __attribute__((ext_vector_type(4))) float f32x4;
typedef __attribute__((ext_vector_type(8))) short short8;

__device__ __forceinline__ unsigned short f2bf(float f) {
  union { float f; unsigned u; } v; v.f = f;
  unsigned r = v.u + 0x7FFFu + ((v.u >> 16) & 1u);
  return (unsigned short)(r >> 16);
}
__device__ __forceinline__ float bf2f(unsigned short h) {
  union { unsigned u; float f; } v; v.u = ((unsigned)h) << 16; return v.f;
}
__device__ __forceinline__ float sigmoidf_(float x) {
  return 1.0f / (1.0f + __builtin_amdgcn_exp2f(x * -1.4426950408889634f));
}
__device__ __forceinline__ float tanhf_(float x) {
  float xc = fminf(fmaxf(x, -8.0f), 8.0f);
  float e = __builtin_amdgcn_exp2f(xc * 2.8853900817779268f);
  return (e - 1.0f) / (e + 1.0f);
}
__device__ __forceinline__ void async16(const void* g, void* l) {
  __builtin_amdgcn_global_load_lds((const __attribute__((address_space(1))) void*)g,
                                   (__attribute__((address_space(3))) void*)l, 16, 0, 0);
}

// ---- merged conversion pass: U, permuted Wcat (3072 x 2048), Wzcat ----
// Wcat n' = bn*192 + w*48 + c*16 + i -> chunk c of h = bn*64 + w*16 + i
// Wzcat row n = [Wz[n] | W_ih[2H+n]]  (z_new@Wz^T + i_z fused, K=2048)
__global__ void k_conv(const float* __restrict__ x, const float* __restrict__ y,
                       const float* __restrict__ Wih, const float* __restrict__ Whh,
                       const float* __restrict__ Wz,
                       unsigned short* __restrict__ U,
                       unsigned short* __restrict__ Wcat,
                       unsigned short* __restrict__ Wzcat) {
  const int stride = gridDim.x * blockDim.x;
  const int tid0 = blockIdx.x * blockDim.x + threadIdx.x;
  const int totalU = BATCH * (HDIM / 4);
  for (int q = tid0; q < totalU; q += stride) {
    int b = q >> 8;
    int c = (q & 255) << 2;
    float4 xv = *(const float4*)(x + (long)b * HDIM + c);
    float4 yv = *(const float4*)(y + (long)b * HDIM + c);
    uint2 xo, yo;
    xo.x = (unsigned)f2bf(xv.x) | ((unsigned)f2bf(xv.y) << 16);
    xo.y = (unsigned)f2bf(xv.z) | ((unsigned)f2bf(xv.w) << 16);
    yo.x = (unsigned)f2bf(yv.x) | ((unsigned)f2bf(yv.y) << 16);
    yo.y = (unsigned)f2bf(yv.z) | ((unsigned)f2bf(yv.w) << 16);
    *(uint2*)(U + (long)b * K1 + c) = xo;
    *(uint2*)(U + (long)b * K1 + HDIM + c) = yo;
  }
  const int totalW = 3072 * (K1 / 4);
  for (int q = tid0; q < totalW; q += stride) {
    int np = q >> 9;
    int kb = (q & 511) << 2;
    int bn = np / 192; int r = np - bn * 192;
    int w = r / 48; int r2 = r - w * 48;
    int c = r2 >> 4, i = r2 & 15;
    int h = bn * 64 + w * 16 + i;
    float4 v;
    if (kb < HDIM) {
      int row = (c == 0) ? h : (c == 1) ? (HDIM + h) : (3 * HDIM + h);
      v = *(const float4*)(Wih + (long)row * HDIM + kb);
    } else {
      int row = (c == 0) ? h : (c == 1) ? (HDIM + h) : (2 * HDIM + h);
      v = *(const float4*)(Whh + (long)row * HDIM + (kb - HDIM));
    }
    uint2 o;
    o.x = (unsigned)f2bf(v.x) | ((unsigned)f2bf(v.y) << 16);
    o.y = (unsigned)f2bf(v.z) | ((unsigned)f2bf(v.w) << 16);
    *(uint2*)(Wcat + (long)np * K1 + kb) = o;
  }
  const int totalZ = HDIM * (K1 / 4);
  for (int q = tid0; q < totalZ; q += stride) {
    int n = q >> 9;
    int kb = (q & 511) << 2;
    float4 v = (kb < HDIM) ? *(const float4*)(Wz + (long)n * HDIM + kb)
                           : *(const float4*)(Wih + (long)(2 * HDIM + n) * HDIM + (kb - HDIM));
    uint2 o;
    o.x = (unsigned)f2bf(v.x) | ((unsigned)f2bf(v.y) << 16);
    o.y = (unsigned)f2bf(v.z) | ((unsigned)f2bf(v.w) << 16);
    *(uint2*)(Wzcat + (long)n * K1 + kb) = o;
  }
}

// ================= gemm1: 8-phase 256x192 core (NB=3) =================
// 8 waves (2M x 4N), per-wave 128x48. BK=64 K-tiles, dbuf (tile&1).
// LDS 112KB = A 2x32KB + B 2x24KB. Per K-tile 4 phases:
//  P1 {12 ds_read: A-MH0(8) + B-frag01(4); lgkm(8); bar; lgkm0; 16 MFMA; bar}
//  P2 {2 ds_read: B-frag2; bar; lgkm0; 8 MFMA; bar}
//  P3 {8 ds_read: A-MH1; stage B(T+2,3 loads); bar; lgkm0; 16 MFMA; bar}
//  P4 {stage A-h0(T+2)+A-h1(T+2); vmcnt(7); bar; lgkm0; 8 MFMA; bar}
// LIVENESS (R13 bugfix): both A halves are read in P1 AND P3 (wave rows =
// wm*128 + MH*64, wm splits halves, MH splits within), so A stages may only
// issue AFTER P3's closing barrier (all waves' A reads drained) -> both A
// half-stages live in P4. B reads finish by P2's closing barrier -> B stage
// at P3 safe. vmcnt(7) at P4 leaves exactly tile T+2's 7 stage-loads in
// flight -> tile T+1 fully landed before its P1 reads (post-P4-barrier).
// XOR swizzle slot=row&7 via pre-swizzled source; 0 bank conflicts.
__global__ __launch_bounds__(512, 2) void k_gemm1(
    const unsigned short* __restrict__ U, const unsigned short* __restrict__ Wcat,
    const float* __restrict__ z, const float* __restrict__ dtp,
    const float* __restrict__ bih, const float* __restrict__ bhh,
    const float* __restrict__ Wdt, const float* __restrict__ bdt,
    float* __restrict__ out, unsigned short* __restrict__ znb,
    unsigned short* __restrict__ sbb) {
  __shared__ char lds[114688];
  char* ldsA = lds;            // 2 x 32KB
  char* ldsB = lds + 65536;    // 2 x 24KB
  const int bid = blockIdx.x;
  const int sid = (bid & 7) * 128 + (bid >> 3);  // XCD-bijective (1024 % 8 == 0)
  const int bm = sid >> 4, bn = sid & 15;
  const long arow0 = (long)bm * 256, brow0 = (long)bn * 192;
  constexpr int NT = K1 / 64;        // 32 K-tiles
  constexpr int NITER = NT / 2;      // 16 iters

  const int t = threadIdx.x, lane = t & 63, wv = t >> 6;
  const int wm = wv >> 2, wn = wv & 3;
  const int rA = lane & 15, kg = lane >> 4;
  const int xsw = (rA & 7) << 4;

  int offA[2][4][2], offB[3][2];
#pragma unroll
  for (int mh = 0; mh < 2; ++mh)
#pragma unroll
    for (int mq = 0; mq < 4; ++mq)
#pragma unroll
      for (int ks = 0; ks < 2; ++ks)
        offA[mh][mq][ks] = wm * 16384 + (mh * 64 + mq * 16 + rA) * 128 +
                           ((ks * 64 + kg * 16) ^ xsw);
#pragma unroll
  for (int nf = 0; nf < 3; ++nf)
#pragma unroll
    for (int ks = 0; ks < 2; ++ks)
      offB[nf][ks] = (wn * 48 + nf * 16 + rA) * 128 + ((ks * 64 + kg * 16) ^ xsw);

  const int t16 = t * 16;
  const int L0 = t16 ^ (((t16 >> 7) & 7) << 4);
  const int r0 = L0 >> 7, c0 = (L0 & 127) >> 1;
  const unsigned short* pA = U + (arow0 + r0) * (long)K1 + c0;
  const unsigned short* pB = Wcat + (brow0 + r0) * (long)K1 + c0;

#define STG_AH_(TT, hh)                                                         \
  do {                                                                          \
    char* db_ = ldsA + ((TT) & 1) * 32768 + (hh) * 16384;                       \
    const unsigned short* sp_ = pA + ((long)(hh) * 128) * K1 + (long)(TT) * 64; \
    async16(sp_, db_ + t16);                                                    \
    async16(sp_ + (long)64 * K1, db_ + 8192 + t16);                             \
  } while (0)
#define STG_B_(TT)                                                              \
  do {                                                                          \
    char* db_ = ldsB + ((TT) & 1) * 24576;                                      \
    const unsigned short* sp_ = pB + (long)(TT) * 64;                           \
    async16(sp_, db_ + t16);                                                    \
    async16(sp_ + (long)64 * K1, db_ + 8192 + t16);                             \
    async16(sp_ + (long)128 * K1, db_ + 16384 + t16);                           \
  } while (0)

#define PH_TOP_                                                                 \
  __builtin_amdgcn_sched_barrier(0);                                            \
  __builtin_amdgcn_s_barrier();                                                 \
  asm volatile("s_waitcnt lgkmcnt(0)" ::: "memory");                            \
  __builtin_amdgcn_sched_barrier(0);                                            \
  __builtin_amdgcn_s_setprio(1)
#define PH_END_                                                                 \
  __builtin_amdgcn_s_setprio(0);                                                \
  __builtin_amdgcn_s_barrier()

  f32x4 acc[8][3];
#pragma unroll
  for (int m = 0; m < 8; ++m)
#pragma unroll
    for (int n = 0; n < 3; ++n) acc[m][n] = (f32x4)(0.0f);

  short8 aF[4][2], bF01[2][2], bF2[2];

  // prologue: stage tiles 0,1 (7 loads each); tile 0 forced landed
  STG_AH_(0, 0); STG_B_(0); STG_AH_(0, 1);
  STG_AH_(1, 0); STG_B_(1); STG_AH_(1, 1);
  asm volatile("s_waitcnt vmcnt(7)" ::: "memory");
  __builtin_amdgcn_sched_barrier(0);
  __builtin_amdgcn_s_barrier();

#pragma unroll 1
  for (int it = 0; it < NITER; ++it) {
    const int T = 2 * it;
    const bool stg = (it < NITER - 1);
#pragma unroll
    for (int half = 0; half < 2; ++half) {
      const int TT = T + half;            // tile index this half-iter
      const char* Ab = ldsA + (TT & 1) * 32768;
      const char* Bb = ldsB + (TT & 1) * 24576;
      const int TS = TT + 2;              // tile to stage
      // ---- P1: A-MH0 + B01 reads; 16 MFMA ----
#pragma unroll
      for (int mq = 0; mq < 4; ++mq)
#pragma unroll
        for (int ks = 0; ks < 2; ++ks)
          aF[mq][ks] = *(const short8*)(Ab + offA[0][mq][ks]);
#pragma unroll
      for (int nf = 0; nf < 2; ++nf)
#pragma unroll
        for (int ks = 0; ks < 2; ++ks)
          bF01[nf][ks] = *(const short8*)(Bb + offB[nf][ks]);
      asm volatile("s_waitcnt lgkmcnt(8)" ::: "memory");
      PH_TOP_;
#pragma unroll
      for (int mq = 0; mq < 4; ++mq)
#pragma unroll
        for (int nf = 0; nf < 2; ++nf)
#pragma unroll
          for (int ks = 0; ks < 2; ++ks)
            acc[mq][nf] = __builtin_amdgcn_mfma_f32_16x16x32_bf16(
                aF[mq][ks], bF01[nf][ks], acc[mq][nf], 0, 0, 0);
      PH_END_;
      // ---- P2: B2 reads; 8 MFMA ----
#pragma unroll
      for (int ks = 0; ks < 2; ++ks)
        bF2[ks] = *(const short8*)(Bb + offB[2][ks]);
      PH_TOP_;
#pragma unroll
      for (int mq = 0; mq < 4; ++mq)
#pragma unroll
        for (int ks = 0; ks < 2; ++ks)
          acc[mq][2] = __builtin_amdgcn_mfma_f32_16x16x32_bf16(
              aF[mq][ks], bF2[ks], acc[mq][2], 0, 0, 0);
      PH_END_;
      // ---- P3: A-MH1 reads; stage B(TS); 16 MFMA ----
#pragma unroll
      for (int mq = 0; mq < 4; ++mq)
#pragma unroll
        for (int ks = 0; ks < 2; ++ks)
          aF[mq][ks] = *(const short8*)(Ab + offA[1][mq][ks]);
      if (stg) STG_B_(TS);
      PH_TOP_;
#pragma unroll
      for (int mq = 0; mq < 4; ++mq)
#pragma unroll
        for (int nf = 0; nf < 2; ++nf)
#pragma unroll
          for (int ks = 0; ks < 2; ++ks)
            acc[4 + mq][nf] = __builtin_amdgcn_mfma_f32_16x16x32_bf16(
                aF[mq][ks], bF01[nf][ks], acc[4 + mq][nf], 0, 0, 0);
      PH_END_;
      // ---- P4: stage A-h0(TS)+A-h1(TS) (post-P3-barrier: all A reads of
      //      this buffer drained by every wave); vmcnt; 8 MFMA ----
      if (stg) {
        STG_AH_(TS, 0);
        STG_AH_(TS, 1);
        asm volatile("s_waitcnt vmcnt(7)" ::: "memory");
      } else if (half == 0) {
        asm volatile("s_waitcnt vmcnt(0)" ::: "memory");
      }
      PH_TOP_;
#pragma unroll
      for (int mq = 0; mq < 4; ++mq)
#pragma unroll
        for (int ks = 0; ks < 2; ++ks)
          acc[4 + mq][2] = __builtin_amdgcn_mfma_f32_16x16x32_bf16(
              aF[mq][ks], bF2[ks], acc[4 + mq][2], 0, 0, 0);
      PH_END_;
    }
  }

  // ---- epilogue: LEM elementwise (3-chunk) ----
  const int q4 = kg << 2;
  const int h = bn * 64 + wn * 16 + rA;
  const int rowbase = bm * 256 + wm * 128;
  const float bi0 = bih[h] + bhh[h];
  const float bi1 = bih[HDIM + h] + bhh[HDIM + h];
  const float bi2 = bih[3 * HDIM + h] + bhh[2 * HDIM + h];
  const float wdt0 = Wdt[0], wdt1 = Wdt[1], bdt0 = bdt[0], bdt1 = bdt[1];
#pragma unroll
  for (int m = 0; m < 8; ++m) {
    const int rowblk = (m >> 2) * 64 + (m & 3) * 16;
#pragma unroll
    for (int j = 0; j < 4; ++j) {
      const int b = rowbase + rowblk + q4 + j;
      const long idx = (long)b * HDIM + h;
      const float dv = dtp[b];
      const float s1 = sigmoidf_(dv * wdt0 + bdt0);
      const float s2 = sigmoidf_(dv * wdt1 + bdt1);
      const float sbar = s1 * sigmoidf_(acc[m][0][j] + bi0);
      const float s = s2 * sigmoidf_(acc[m][1][j] + bi1);
      const float zt = tanhf_(acc[m][2][j] + bi2);
      const float znew = (1.0f - s) * z[idx] + s * zt;
      out[(long)BATCH * HDIM + idx] = znew;  // z_new output (f32)
      znb[idx] = f2bf(znew);                  // A-left-half for phase 2
      sbb[idx] = f2bf(sbar);
    }
  }
#undef STG_AH_
#undef STG_B_
#undef PH_TOP_
#undef PH_END_
}

// ======= gemm2: R12 5-buffer-ring core, K-fused [z_new|x] (256x128) =======
template <int NB, int KSPLIT, bool BSPLIT>
__device__ __forceinline__ void gemm_core(
    const unsigned short* __restrict__ A1, int strA1,
    const unsigned short* __restrict__ A2, int strA2,
    const unsigned short* __restrict__ Bg,
    long arow0, long brow0, char* lds, f32x4 acc[8][NB]) {
  constexpr int NT = 64;
  constexpr int ABY = 16384;
  constexpr int BBY = NB * 4096;
  char* ldsA = lds;
  char* ldsB = lds + 5 * ABY;
  const int t = threadIdx.x, lane = t & 63, wv = t >> 6;
  const int wm = wv >> 2, wn = wv & 3;
  const int rA = lane & 15;
  const int cphys = ((lane >> 4) << 4) ^ (((rA >> 1) & 3) << 4);
  const int t16 = t * 16;
  const bool blo = (t < 256);

  const int sA = t16 ^ (((t16 >> 7) & 3) << 4);
  const int rA0 = sA >> 6, cA0 = (sA & 63) >> 1;
  const unsigned short* pA1a = A1 + (arow0 + rA0) * (long)strA1 + cA0;
  const unsigned short* pA1b = A1 + (arow0 + rA0 + 128) * (long)strA1 + cA0;
  const unsigned short* pA2a = A2 + (arow0 + rA0) * (long)strA2 + cA0;
  const unsigned short* pA2b = A2 + (arow0 + rA0 + 128) * (long)strA2 + cA0;

  const int Lb0 = BSPLIT ? (blo ? t16 : t16 + 4096) : t16;
  const int Lb1 = t16 + 4096;
  const int sB0 = Lb0 ^ (((Lb0 >> 7) & 3) << 4);
  const int sB1 = Lb1 ^ (((Lb1 >> 7) & 3) << 4);
  const unsigned short* pBg0 = Bg + (brow0 + (sB0 >> 6)) * (long)K1 + ((sB0 & 63) >> 1);
  const unsigned short* pBg1 = Bg + (brow0 + (sB1 >> 6)) * (long)K1 + ((sB1 & 63) >> 1);

  int offA[8], offB[NB];
#pragma unroll
  for (int m = 0; m < 8; ++m)
    offA[m] = (wm * 128 + m * 16 + rA) * 64 + cphys;
#pragma unroll
  for (int n = 0; n < NB; ++n)
    offB[n] = (wn * (NB * 16) + n * 16 + rA) * 64 + cphys;

#define STAGE_TO_(AB_, BB_, TT)                                           \
  do {                                                                    \
    if ((TT) < KSPLIT) {                                                  \
      async16(pA1a + (long)(TT) * 32, (AB_) + t16);                       \
      async16(pA1b + (long)(TT) * 32, (AB_) + 8192 + t16);                \
    } else {                                                              \
      async16(pA2a + (long)((TT) - KSPLIT) * 32, (AB_) + t16);            \
      async16(pA2b + (long)((TT) - KSPLIT) * 32, (AB_) + 8192 + t16);     \
    }                                                                     \
    async16(pBg0 + (long)(TT) * 32, (BB_) + Lb0);                         \
    if (BSPLIT && blo) async16(pBg1 + (long)(TT) * 32, (BB_) + Lb1);      \
  } while (0)
#define VM_STEADY_ asm volatile("s_waitcnt vmcnt(6)" ::: "memory")
#define VM_TAIL1_  asm volatile("s_waitcnt vmcnt(3)" ::: "memory")
#define VM_TAIL0_  asm volatile("s_waitcnt vmcnt(0)" ::: "memory")

  STAGE_TO_(ldsA, ldsB, 0);
  STAGE_TO_(ldsA + ABY, ldsB + BBY, 1);
  STAGE_TO_(ldsA + 2 * ABY, ldsB + 2 * BBY, 2);
  VM_STEADY_;
  __builtin_amdgcn_s_barrier();

  const char* rdA = ldsA;
  const char* rdB = ldsB;
  char* stA = ldsA + 3 * ABY;
  char* stB = ldsB + 3 * BBY;
  const char* ldsAend = ldsA + 5 * ABY;
  const char* ldsBend = ldsB + 5 * BBY;

#pragma unroll 1
  for (int kt = 0; kt < NT; ++kt) {
    short8 af_[8], bf_[NB];
#pragma unroll
    for (int m = 0; m < 8; ++m) af_[m] = *(const short8*)(rdA + offA[m]);
#pragma unroll
    for (int n = 0; n < NB; ++n) bf_[n] = *(const short8*)(rdB + offB[n]);
    if (kt < NT - 3) {
      STAGE_TO_(stA, stB, kt + 3);
      VM_STEADY_;
    } else if (kt == NT - 3) {
      VM_TAIL1_;
    } else if (kt == NT - 2) {
      VM_TAIL0_;
    }
    __builtin_amdgcn_s_barrier();
    __builtin_amdgcn_s_setprio(1);
#pragma unroll
    for (int m = 0; m < 8; ++m)
#pragma unroll
      for (int n = 0; n < NB; ++n)
        acc[m][n] = __builtin_amdgcn_mfma_f32_16x16x32_bf16(
            af_[m], bf_[n], acc[m][n], 0, 0, 0);
    __builtin_amdgcn_s_setprio(0);
    rdA += ABY; rdA = (rdA == ldsAend) ? ldsA : rdA;
    rdB += BBY; rdB = (rdB == ldsBend) ? ldsB : rdB;
    stA += ABY; stA = (stA == ldsAend) ? (char*)ldsA : stA;
    stB += BBY; stB = (stB == ldsBend) ? (char*)ldsB : stB;
  }
#undef STAGE_TO_
#undef VM_STEADY_
#undef VM_TAIL1_
#undef VM_TAIL0_
}

__global__ __launch_bounds__(512, 2) void k_gemm2(
    const unsigned short* __restrict__ Zn, const unsigned short* __restrict__ U,
    const unsigned short* __restrict__ Wzcat, const unsigned short* __restrict__ sbb,
    const float* __restrict__ yin, const float* __restrict__ bz,
    float* __restrict__ out) {
  __shared__ char lds[122880];  // 5x16KB A + 5x8KB B
  const int bid = blockIdx.x;
  const int sid = (bid & 7) * 64 + (bid >> 3);  // 512 % 8 == 0
  const int bm = sid >> 3, bn = sid & 7;
  f32x4 acc[8][2];
#pragma unroll
  for (int m = 0; m < 8; ++m)
#pragma unroll
    for (int n = 0; n < 2; ++n) acc[m][n] = (f32x4)(0.0f);

  gemm_core<2, 32, false>(Zn, HDIM, U, K1, Wzcat, (long)bm * 256, (long)bn * 128, lds, acc);

  const int t = threadIdx.x, lane = t & 63, wv = t >> 6;
  const int wm = wv >> 2, wn = wv & 3;
  const int rA = lane & 15, q4 = (lane >> 4) << 2;
  const int rowbase = bm * 256 + wm * 128;
#pragma unroll
  for (int n = 0; n < 2; ++n) {
    const int hc = bn * 128 + wn * 32 + n * 16 + rA;
    const float bzv = bz[hc];
#pragma unroll
    for (int m = 0; m < 8; ++m) {
#pragma unroll
      for (int j = 0; j < 4; ++j) {
        const int b = rowbase + m * 16 + q4 + j;
        const long idx = (long)b * HDIM + hc;
        const float tv = tanhf_(acc[m][n][j] + bzv);
        const float sb = bf2f(sbb[idx]);
        out[idx] = (1.0f - sb) * yin[idx] + sb * tv;  // y_new
      }
    }
  }
}

extern "C" void kernel_launch(void* const* d_in, const int* in_sizes, int n_in,
                              void* d_out, int out_size, void* d_ws, size_t ws_size,
                              hipStream_t stream) {
  const float* x   = (const float*)d_in[0];
  const float* y   = (const float*)d_in[1];
  const float* z   = (const float*)d_in[2];
  const float* dtp = (const float*)d_in[3];
  const float* Wih = (const float*)d_in[4];
  const float* bih = (const float*)d_in[5];
  const float* Whh = (const float*)d_in[6];
  const float* bhh = (const float*)d_in[7];
  const float* Wz  = (const float*)d_in[8];
  const float* bz  = (const float*)d_in[9];
  const float* Wdt = (const float*)d_in[10];
  const float* bdt = (const float*)d_in[11];

  char* ws = (char*)d_ws;
  unsigned short* U     = (unsigned short*)(ws);              // 67,108,864 B
  unsigned short* Wcat  = (unsigned short*)(ws + 67108864);   // 12,582,912 B
  unsigned short* Wzcat = (unsigned short*)(ws + 79691776);   //  4,194,304 B
  unsigned short* Znb   = (unsigned short*)(ws + 83886080);   // 33,554,432 B
  unsigned short* Sbb   = (unsigned short*)(ws + 117440512);  // 33,554,432 B -> 150,994,944 B
  float* out = (float*)d_out;

  k_conv<<<2048, 256, 0, stream>>>(x, y, Wih, Whh, Wz, U, Wcat, Wzcat);
  k_gemm1<<<1024, 512, 0, stream>>>(U, Wcat, z, dtp, bih, bhh, Wdt, bdt, out, Znb, Sbb);
  k_gemm2<<<512, 512, 0, stream>>>(Znb, U, Wzcat, Sbb, y, bz, out);
}

// Round 15
// 324.884 us; speedup vs baseline: 1.4968x; 1.1776x over previous
//
#include <hip/hip_runtime.h>
#include <hip/hip_bf16.h>

#define BATCH 16384
#define HDIM  1024
#define K1    2048

typedef __attribute__((ext_vector_type(4))) float f32x4;
typedef __attribute__((ext_vector_type(4))) int i32x4;
typedef __attribute__((ext_vector_type(8))) short short8;

__device__ __forceinline__ unsigned short f2bf(float f) {
  union { float f; unsigned u; } v; v.f = f;
  unsigned r = v.u + 0x7FFFu + ((v.u >> 16) & 1u);
  return (unsigned short)(r >> 16);
}
__device__ __forceinline__ float bf2f(unsigned short h) {
  union { unsigned u; float f; } v; v.u = ((unsigned)h) << 16; return v.f;
}
__device__ __forceinline__ float sigmoidf_(float x) {
  return 1.0f / (1.0f + __builtin_amdgcn_exp2f(x * -1.4426950408889634f));
}
__device__ __forceinline__ float tanhf_(float x) {
  float xc = fminf(fmaxf(x, -8.0f), 8.0f);
  float e = __builtin_amdgcn_exp2f(xc * 2.8853900817779268f);
  return (e - 1.0f) / (e + 1.0f);
}
__device__ __forceinline__ void async16(const void* g, void* l) {
  __builtin_amdgcn_global_load_lds((const __attribute__((address_space(1))) void*)g,
                                   (__attribute__((address_space(3))) void*)l, 16, 0, 0);
}
__device__ __forceinline__ int q8p(float4 v, float s) {
  int a = __float2int_rn(fminf(fmaxf(v.x * s, -127.f), 127.f));
  int b = __float2int_rn(fminf(fmaxf(v.y * s, -127.f), 127.f));
  int c = __float2int_rn(fminf(fmaxf(v.z * s, -127.f), 127.f));
  int d = __float2int_rn(fminf(fmaxf(v.w * s, -127.f), 127.f));
  return (a & 255) | ((b & 255) << 8) | ((c & 255) << 16) | ((d & 255) << 24);
}

#define QXS (127.0f / 6.0f)
#define QWS (127.0f / 0.03125f)
#define SXW ((6.0f / 127.0f) * (0.03125f / 127.0f))

// ---- merged conversion: U8 (i8 [x|y] 16384x2048), Xbf (bf16 x, stride 1024),
//      W8 (i8 permuted Wcat 3072x2048), Wzcat (bf16 [Wz|Wih_2H] 1024x2048) ----
// Wcat n' = bn*192 + w*48 + c*16 + i -> chunk c of h = bn*64 + w*16 + i
__global__ void k_conv(const float* __restrict__ x, const float* __restrict__ y,
                       const float* __restrict__ Wih, const float* __restrict__ Whh,
                       const float* __restrict__ Wz,
                       char* __restrict__ U8, unsigned short* __restrict__ Xbf,
                       char* __restrict__ W8, unsigned short* __restrict__ Wzcat) {
  const int stride = gridDim.x * blockDim.x;
  const int tid0 = blockIdx.x * blockDim.x + threadIdx.x;
  const int totalU = BATCH * (HDIM / 4);
  for (int q = tid0; q < totalU; q += stride) {
    int b = q >> 8;
    int c = (q & 255) << 2;
    float4 xv = *(const float4*)(x + (long)b * HDIM + c);
    float4 yv = *(const float4*)(y + (long)b * HDIM + c);
    *(int*)(U8 + (long)b * K1 + c) = q8p(xv, QXS);
    *(int*)(U8 + (long)b * K1 + HDIM + c) = q8p(yv, QXS);
    uint2 xo;
    xo.x = (unsigned)f2bf(xv.x) | ((unsigned)f2bf(xv.y) << 16);
    xo.y = (unsigned)f2bf(xv.z) | ((unsigned)f2bf(xv.w) << 16);
    *(uint2*)(Xbf + (long)b * HDIM + c) = xo;
  }
  const int totalW = 3072 * (K1 / 4);
  for (int q = tid0; q < totalW; q += stride) {
    int np = q >> 9;
    int kb = (q & 511) << 2;
    int bn = np / 192; int r = np - bn * 192;
    int w = r / 48; int r2 = r - w * 48;
    int c = r2 >> 4, i = r2 & 15;
    int h = bn * 64 + w * 16 + i;
    float4 v;
    if (kb < HDIM) {
      int row = (c == 0) ? h : (c == 1) ? (HDIM + h) : (3 * HDIM + h);
      v = *(const float4*)(Wih + (long)row * HDIM + kb);
    } else {
      int row = (c == 0) ? h : (c == 1) ? (HDIM + h) : (2 * HDIM + h);
      v = *(const float4*)(Whh + (long)row * HDIM + (kb - HDIM));
    }
    *(int*)(W8 + (long)np * K1 + kb) = q8p(v, QWS);
  }
  const int totalZ = HDIM * (K1 / 4);
  for (int q = tid0; q < totalZ; q += stride) {
    int n = q >> 9;
    int kb = (q & 511) << 2;
    float4 v = (kb < HDIM) ? *(const float4*)(Wz + (long)n * HDIM + kb)
                           : *(const float4*)(Wih + (long)(2 * HDIM + n) * HDIM + (kb - HDIM));
    uint2 o;
    o.x = (unsigned)f2bf(v.x) | ((unsigned)f2bf(v.y) << 16);
    o.y = (unsigned)f2bf(v.z) | ((unsigned)f2bf(v.w) << 16);
    *(uint2*)(Wzcat + (long)n * K1 + kb) = o;
  }
}

// ===== gemm1: i8 port of the measured-best R9 core (256x192, 24-MFMA) =====
// BK=64 i8 K-tiles are byte-identical to BK=32 bf16 tiles: A 256x64B=16KB,
// B 192x64B=12KB, 64B rows, same XOR swizzle (slot=rA&7 via inverse-swizzled
// source), same 16B fragment reads, same vmcnt counts. 4 buffers, staging
// distance 3, per kt: {11 ds_read; stage(kt+3); vmcnt(8/6 lo/hi)+lgkm(0);
// barrier; setprio(1); 24 x mfma_i32_16x16x64_i8; setprio(0)}. NT=32.
__global__ __launch_bounds__(512, 2) void k_gemm1(
    const char* __restrict__ U8, const char* __restrict__ W8,
    const float* __restrict__ z, const float* __restrict__ dtp,
    const float* __restrict__ bih, const float* __restrict__ bhh,
    const float* __restrict__ Wdt, const float* __restrict__ bdt,
    float* __restrict__ out, unsigned short* __restrict__ znb,
    unsigned short* __restrict__ sbb) {
  __shared__ char lds[114688];  // A 4x16KB + B 4x12KB
  char* ldsA = lds;
  char* ldsB = lds + 65536;
  const int bid = blockIdx.x;
  const int sid = (bid & 7) * 128 + (bid >> 3);  // XCD-bijective (1024 % 8 == 0)
  const int bm = sid >> 4, bn = sid & 15;
  const long arow0 = (long)bm * 256, brow0 = (long)bn * 192;
  constexpr int NT = 32;

  const int t = threadIdx.x, lane = t & 63, wv = t >> 6;
  const int wm = wv >> 2, wn = wv & 3;
  const int rA = lane & 15;
  const int cphys = ((lane >> 4) << 4) ^ (((rA >> 1) & 3) << 4);
  const int t16 = t * 16;
  const bool blo = (t < 256);

  // A staging source (inverse-swizzled), bytes
  const int sA = t16 ^ (((t16 >> 7) & 3) << 4);
  const int rA0 = sA >> 6, cA0 = sA & 63;
  const char* pAa = U8 + (arow0 + rA0) * (long)K1 + cA0;
  const char* pAb = U8 + (arow0 + rA0 + 128) * (long)K1 + cA0;

  // B staging: lo waves 2 loads (L=t16, t16+4096), hi waves 1 (L=t16+4096)
  const int Lb0 = blo ? t16 : t16 + 4096;
  const int Lb1 = t16 + 4096;
  const int sB0 = Lb0 ^ (((Lb0 >> 7) & 3) << 4);
  const int sB1 = Lb1 ^ (((Lb1 >> 7) & 3) << 4);
  const char* pBg0 = W8 + (brow0 + (sB0 >> 6)) * (long)K1 + (sB0 & 63);
  const char* pBg1 = W8 + (brow0 + (sB1 >> 6)) * (long)K1 + (sB1 & 63);

  int offA[8], offB[3];
#pragma unroll
  for (int m = 0; m < 8; ++m)
    offA[m] = (wm * 128 + m * 16 + rA) * 64 + cphys;
#pragma unroll
  for (int n = 0; n < 3; ++n)
    offB[n] = (wn * 48 + n * 16 + rA) * 64 + cphys;

#define STAGE_(TT)                                                        \
  do {                                                                    \
    char* ab_ = ldsA + ((TT) & 3) * 16384;                                \
    char* bb_ = ldsB + ((TT) & 3) * 12288;                                \
    async16(pAa + (long)(TT) * 64, ab_ + t16);                            \
    async16(pAb + (long)(TT) * 64, ab_ + 8192 + t16);                     \
    async16(pBg0 + (long)(TT) * 64, bb_ + Lb0);                           \
    if (blo) async16(pBg1 + (long)(TT) * 64, bb_ + Lb1);                  \
  } while (0)
#define WSTEADY_                                                          \
  do {                                                                    \
    if (blo) asm volatile("s_waitcnt vmcnt(8) lgkmcnt(0)" ::: "memory");  \
    else     asm volatile("s_waitcnt vmcnt(6) lgkmcnt(0)" ::: "memory");  \
  } while (0)
#define WTAIL1_                                                           \
  do {                                                                    \
    if (blo) asm volatile("s_waitcnt vmcnt(4) lgkmcnt(0)" ::: "memory");  \
    else     asm volatile("s_waitcnt vmcnt(3) lgkmcnt(0)" ::: "memory");  \
  } while (0)
#define WTAIL0_ asm volatile("s_waitcnt vmcnt(0) lgkmcnt(0)" ::: "memory")
#define WLAST_  asm volatile("s_waitcnt lgkmcnt(0)" ::: "memory")

  i32x4 acc[8][3];
#pragma unroll
  for (int m = 0; m < 8; ++m)
#pragma unroll
    for (int n = 0; n < 3; ++n) acc[m][n] = (i32x4)(0);

  // prologue: stage K-tiles 0,1,2
  STAGE_(0);
  STAGE_(1);
  STAGE_(2);
  WSTEADY_;
  __builtin_amdgcn_s_barrier();

#pragma unroll 1
  for (int kt = 0; kt < NT; ++kt) {
    const char* Ab_ = ldsA + (kt & 3) * 16384;
    const char* Bb_ = ldsB + (kt & 3) * 12288;
    i32x4 af_[8], bf_[3];
#pragma unroll
    for (int m = 0; m < 8; ++m) af_[m] = *(const i32x4*)(Ab_ + offA[m]);
#pragma unroll
    for (int n = 0; n < 3; ++n) bf_[n] = *(const i32x4*)(Bb_ + offB[n]);
    if (kt < NT - 3) {
      STAGE_(kt + 3);
      WSTEADY_;
    } else if (kt == NT - 3) {
      WTAIL1_;
    } else if (kt == NT - 2) {
      WTAIL0_;
    } else {
      WLAST_;
    }
    __builtin_amdgcn_s_barrier();
    __builtin_amdgcn_sched_barrier(0);
    __builtin_amdgcn_s_setprio(1);
#pragma unroll
    for (int m = 0; m < 8; ++m)
#pragma unroll
      for (int n = 0; n < 3; ++n)
        acc[m][n] = __builtin_amdgcn_mfma_i32_16x16x64_i8(
            af_[m], bf_[n], acc[m][n], 0, 0, 0);
    __builtin_amdgcn_s_setprio(0);
  }
#undef STAGE_
#undef WSTEADY_
#undef WTAIL1_
#undef WTAIL0_
#undef WLAST_

  // ---- epilogue: dequant + LEM elementwise ----
  const int q4 = (lane >> 4) << 2;
  const int h = bn * 64 + wn * 16 + rA;
  const int rowbase = bm * 256 + wm * 128;
  const float bi0 = bih[h] + bhh[h];
  const float bi1 = bih[HDIM + h] + bhh[HDIM + h];
  const float bi2 = bih[3 * HDIM + h] + bhh[2 * HDIM + h];
  const float wdt0 = Wdt[0], wdt1 = Wdt[1], bdt0 = bdt[0], bdt1 = bdt[1];
#pragma unroll
  for (int m = 0; m < 8; ++m) {
#pragma unroll
    for (int j = 0; j < 4; ++j) {
      const int b = rowbase + m * 16 + q4 + j;
      const long idx = (long)b * HDIM + h;
      const float dv = dtp[b];
      const float s1 = sigmoidf_(dv * wdt0 + bdt0);
      const float s2 = sigmoidf_(dv * wdt1 + bdt1);
      const float g0 = (float)acc[m][0][j] * SXW + bi0;
      const float g1 = (float)acc[m][1][j] * SXW + bi1;
      const float g2 = (float)acc[m][2][j] * SXW + bi2;
      const float sbar = s1 * sigmoidf_(g0);
      const float s = s2 * sigmoidf_(g1);
      const float zt = tanhf_(g2);
      const float znew = (1.0f - s) * z[idx] + s * zt;
      out[(long)BATCH * HDIM + idx] = znew;  // z_new output (f32)
      znb[idx] = f2bf(znew);                  // A-left-half for phase 2
      sbb[idx] = f2bf(sbar);
    }
  }
}

// ======= gemm2: bf16 R9 core, K-fused [z_new|x] (256x128 tiles) =======
template <int NB, int KSPLIT>
__device__ __forceinline__ void gemm_core(
    const unsigned short* __restrict__ A1, int strA1,
    const unsigned short* __restrict__ A2, int strA2,
    const unsigned short* __restrict__ Bg,
    long arow0, long brow0, char* lds, f32x4 acc[8][NB]) {
  constexpr int NT = 64;
  constexpr int BBY = NB * 4096;
  char* ldsA = lds;
  char* ldsB = lds + 65536;
  const int t = threadIdx.x, lane = t & 63, wv = t >> 6;
  const int wm = wv >> 2, wn = wv & 3;
  const int rA = lane & 15;
  const int cphys = ((lane >> 4) << 4) ^ (((rA >> 1) & 3) << 4);
  const int t16 = t * 16;

  const int sA = t16 ^ (((t16 >> 7) & 3) << 4);
  const int rA0 = sA >> 6, cA0 = (sA & 63) >> 1;
  const unsigned short* pA1a = A1 + (arow0 + rA0) * (long)strA1 + cA0;
  const unsigned short* pA1b = A1 + (arow0 + rA0 + 128) * (long)strA1 + cA0;
  const unsigned short* pA2a = A2 + (arow0 + rA0) * (long)strA2 + cA0;
  const unsigned short* pA2b = A2 + (arow0 + rA0 + 128) * (long)strA2 + cA0;

  const int Lb0 = t16;
  const int sB0 = Lb0 ^ (((Lb0 >> 7) & 3) << 4);
  const unsigned short* pBg0 = Bg + (brow0 + (sB0 >> 6)) * (long)K1 + ((sB0 & 63) >> 1);

  int offA[8], offB[NB];
#pragma unroll
  for (int m = 0; m < 8; ++m)
    offA[m] = (wm * 128 + m * 16 + rA) * 64 + cphys;
#pragma unroll
  for (int n = 0; n < NB; ++n)
    offB[n] = (wn * (NB * 16) + n * 16 + rA) * 64 + cphys;

#define STAGE2_(TT)                                                       \
  do {                                                                    \
    char* ab_ = ldsA + ((TT) & 3) * 16384;                                \
    char* bb_ = ldsB + ((TT) & 3) * BBY;                                  \
    if ((TT) < KSPLIT) {                                                  \
      async16(pA1a + (long)(TT) * 32, ab_ + t16);                         \
      async16(pA1b + (long)(TT) * 32, ab_ + 8192 + t16);                  \
    } else {                                                              \
      async16(pA2a + (long)((TT) - KSPLIT) * 32, ab_ + t16);              \
      async16(pA2b + (long)((TT) - KSPLIT) * 32, ab_ + 8192 + t16);       \
    }                                                                     \
    async16(pBg0 + (long)(TT) * 32, bb_ + Lb0);                           \
  } while (0)
#define W2S_ asm volatile("s_waitcnt vmcnt(6) lgkmcnt(0)" ::: "memory")
#define W2A_ asm volatile("s_waitcnt vmcnt(3) lgkmcnt(0)" ::: "memory")
#define W2B_ asm volatile("s_waitcnt vmcnt(0) lgkmcnt(0)" ::: "memory")
#define W2C_ asm volatile("s_waitcnt lgkmcnt(0)" ::: "memory")

  STAGE2_(0);
  STAGE2_(1);
  STAGE2_(2);
  W2S_;
  __builtin_amdgcn_s_barrier();

#pragma unroll 1
  for (int kt = 0; kt < NT; ++kt) {
    const char* Ab_ = ldsA + (kt & 3) * 16384;
    const char* Bb_ = ldsB + (kt & 3) * BBY;
    short8 af_[8], bf_[NB];
#pragma unroll
    for (int m = 0; m < 8; ++m) af_[m] = *(const short8*)(Ab_ + offA[m]);
#pragma unroll
    for (int n = 0; n < NB; ++n) bf_[n] = *(const short8*)(Bb_ + offB[n]);
    if (kt < NT - 3) {
      STAGE2_(kt + 3);
      W2S_;
    } else if (kt == NT - 3) {
      W2A_;
    } else if (kt == NT - 2) {
      W2B_;
    } else {
      W2C_;
    }
    __builtin_amdgcn_s_barrier();
    __builtin_amdgcn_sched_barrier(0);
    __builtin_amdgcn_s_setprio(1);
#pragma unroll
    for (int m = 0; m < 8; ++m)
#pragma unroll
      for (int n = 0; n < NB; ++n)
        acc[m][n] = __builtin_amdgcn_mfma_f32_16x16x32_bf16(
            af_[m], bf_[n], acc[m][n], 0, 0, 0);
    __builtin_amdgcn_s_setprio(0);
  }
#undef STAGE2_
#undef W2S_
#undef W2A_
#undef W2B_
#undef W2C_
}

__global__ __launch_bounds__(512, 2) void k_gemm2(
    const unsigned short* __restrict__ Zn, const unsigned short* __restrict__ Xbf,
    const unsigned short* __restrict__ Wzcat, const unsigned short* __restrict__ sbb,
    const float* __restrict__ yin, const float* __restrict__ bz,
    float* __restrict__ out) {
  __shared__ char lds[98304];  // A 4x16KB + B 4x8KB
  const int bid = blockIdx.x;
  const int sid = (bid & 7) * 64 + (bid >> 3);  // 512 % 8 == 0
  const int bm = sid >> 3, bn = sid & 7;
  f32x4 acc[8][2];
#pragma unroll
  for (int m = 0; m < 8; ++m)
#pragma unroll
    for (int n = 0; n < 2; ++n) acc[m][n] = (f32x4)(0.0f);

  // A: kt<32 -> Znb (stride 1024), kt>=32 -> Xbf (stride 1024)
  gemm_core<2, 32>(Zn, HDIM, Xbf, HDIM, Wzcat, (long)bm * 256, (long)bn * 128, lds, acc);

  const int t = threadIdx.x, lane = t & 63, wv = t >> 6;
  const int wm = wv >> 2, wn = wv & 3;
  const int rA = lane & 15, q4 = (lane >> 4) << 2;
  const int rowbase = bm * 256 + wm * 128;
#pragma unroll
  for (int n = 0; n < 2; ++n) {
    const int hc = bn * 128 + wn * 32 + n * 16 + rA;
    const float bzv = bz[hc];
#pragma unroll
    for (int m = 0; m < 8; ++m) {
#pragma unroll
      for (int j = 0; j < 4; ++j) {
        const int b = rowbase + m * 16 + q4 + j;
        const long idx = (long)b * HDIM + hc;
        const float tv = tanhf_(acc[m][n][j] + bzv);
        const float sb = bf2f(sbb[idx]);
        out[idx] = (1.0f - sb) * yin[idx] + sb * tv;  // y_new
      }
    }
  }
}

extern "C" void kernel_launch(void* const* d_in, const int* in_sizes, int n_in,
                              void* d_out, int out_size, void* d_ws, size_t ws_size,
                              hipStream_t stream) {
  const float* x   = (const float*)d_in[0];
  const float* y   = (const float*)d_in[1];
  const float* z   = (const float*)d_in[2];
  const float* dtp = (const float*)d_in[3];
  const float* Wih = (const float*)d_in[4];
  const float* bih = (const float*)d_in[5];
  const float* Whh = (const float*)d_in[6];
  const float* bhh = (const float*)d_in[7];
  const float* Wz  = (const float*)d_in[8];
  const float* bz  = (const float*)d_in[9];
  const float* Wdt = (const float*)d_in[10];
  const float* bdt = (const float*)d_in[11];

  char* ws = (char*)d_ws;
  char*           U8    = ws;                                  // 33,554,432 B
  unsigned short* Xbf   = (unsigned short*)(ws + 33554432);    // 33,554,432 B
  char*           W8    = ws + 67108864;                       //  6,291,456 B
  unsigned short* Wzcat = (unsigned short*)(ws + 73400320);    //  4,194,304 B
  unsigned short* Znb   = (unsigned short*)(ws + 77594624);    // 33,554,432 B
  unsigned short* Sbb   = (unsigned short*)(ws + 111149056);   // 33,554,432 B -> 144,703,488 B
  float* out = (float*)d_out;

  k_conv<<<2048, 256, 0, stream>>>(x, y, Wih, Whh, Wz, U8, Xbf, W8, Wzcat);
  k_gemm1<<<1024, 512, 0, stream>>>(U8, W8, z, dtp, bih, bhh, Wdt, bdt, out, Znb, Sbb);
  k_gemm2<<<512, 512, 0, stream>>>(Znb, Xbf, Wzcat, Sbb, y, bz, out);
}

// Round 16
// 261.980 us; speedup vs baseline: 1.8562x; 1.2401x over previous
//
#include <hip/hip_runtime.h>
#include <hip/hip_bf16.h>

#define BATCH 16384
#define HDIM  1024
#define K1    2048

typedef __attribute__((ext_vector_type(4))) float f32x4;
typedef __attribute__((ext_vector_type(4))) int i32x4;

__device__ __forceinline__ unsigned short f2bf(float f) {
  union { float f; unsigned u; } v; v.f = f;
  unsigned r = v.u + 0x7FFFu + ((v.u >> 16) & 1u);
  return (unsigned short)(r >> 16);
}
__device__ __forceinline__ float bf2f(unsigned short h) {
  union { unsigned u; float f; } v; v.u = ((unsigned)h) << 16; return v.f;
}
__device__ __forceinline__ float sigmoidf_(float x) {
  return 1.0f / (1.0f + __builtin_amdgcn_exp2f(x * -1.4426950408889634f));
}
__device__ __forceinline__ float tanhf_(float x) {
  float xc = fminf(fmaxf(x, -8.0f), 8.0f);
  float e = __builtin_amdgcn_exp2f(xc * 2.8853900817779268f);
  return (e - 1.0f) / (e + 1.0f);
}
__device__ __forceinline__ void async16(const void* g, void* l) {
  __builtin_amdgcn_global_load_lds((const __attribute__((address_space(1))) void*)g,
                                   (__attribute__((address_space(3))) void*)l, 16, 0, 0);
}
__device__ __forceinline__ int q8p(float4 v, float s) {
  int a = __float2int_rn(fminf(fmaxf(v.x * s, -127.f), 127.f));
  int b = __float2int_rn(fminf(fmaxf(v.y * s, -127.f), 127.f));
  int c = __float2int_rn(fminf(fmaxf(v.z * s, -127.f), 127.f));
  int d = __float2int_rn(fminf(fmaxf(v.w * s, -127.f), 127.f));
  return (a & 255) | ((b & 255) << 8) | ((c & 255) << 16) | ((d & 255) << 24);
}

#define QXS (127.0f / 6.0f)
#define QWS (127.0f / 0.03125f)
#define SXW ((6.0f / 127.0f) * (0.03125f / 127.0f))

// ---- merged conversion: U8 (i8 [x|y] 16384x2048), W8 (i8 permuted Wcat
//      3072x2048), Wz8 (i8 [Wz|Wih_2H] 1024x2048) ----
// Wcat n' = bn*192 + w*48 + c*16 + i -> chunk c of h = bn*64 + w*16 + i
__global__ void k_conv(const float* __restrict__ x, const float* __restrict__ y,
                       const float* __restrict__ Wih, const float* __restrict__ Whh,
                       const float* __restrict__ Wz,
                       char* __restrict__ U8, char* __restrict__ W8,
                       char* __restrict__ Wz8) {
  const int stride = gridDim.x * blockDim.x;
  const int tid0 = blockIdx.x * blockDim.x + threadIdx.x;
  const int totalU = BATCH * (HDIM / 4);
  for (int q = tid0; q < totalU; q += stride) {
    int b = q >> 8;
    int c = (q & 255) << 2;
    float4 xv = *(const float4*)(x + (long)b * HDIM + c);
    float4 yv = *(const float4*)(y + (long)b * HDIM + c);
    *(int*)(U8 + (long)b * K1 + c) = q8p(xv, QXS);
    *(int*)(U8 + (long)b * K1 + HDIM + c) = q8p(yv, QXS);
  }
  const int totalW = 3072 * (K1 / 4);
  for (int q = tid0; q < totalW; q += stride) {
    int np = q >> 9;
    int kb = (q & 511) << 2;
    int bn = np / 192; int r = np - bn * 192;
    int w = r / 48; int r2 = r - w * 48;
    int c = r2 >> 4, i = r2 & 15;
    int h = bn * 64 + w * 16 + i;
    float4 v;
    if (kb < HDIM) {
      int row = (c == 0) ? h : (c == 1) ? (HDIM + h) : (3 * HDIM + h);
      v = *(const float4*)(Wih + (long)row * HDIM + kb);
    } else {
      int row = (c == 0) ? h : (c == 1) ? (HDIM + h) : (2 * HDIM + h);
      v = *(const float4*)(Whh + (long)row * HDIM + (kb - HDIM));
    }
    *(int*)(W8 + (long)np * K1 + kb) = q8p(v, QWS);
  }
  const int totalZ = HDIM * (K1 / 4);
  for (int q = tid0; q < totalZ; q += stride) {
    int n = q >> 9;
    int kb = (q & 511) << 2;
    float4 v = (kb < HDIM) ? *(const float4*)(Wz + (long)n * HDIM + kb)
                           : *(const float4*)(Wih + (long)(2 * HDIM + n) * HDIM + (kb - HDIM));
    *(int*)(Wz8 + (long)n * K1 + kb) = q8p(v, QWS);
  }
}

// ===== gemm1: i8 R9 core (256x192 tile, 24 MFMA/barrier), NT=32 =====
// BK=64 i8 K-tiles byte-identical to BK=32 bf16: A 256x64B=16KB,
// B 192x64B=12KB, 64B rows, XOR swizzle slot=rA&7 via inverse-swizzled
// source, 16B fragment reads, same vmcnt counts. 4 buffers, distance 3.
__global__ __launch_bounds__(512, 2) void k_gemm1(
    const char* __restrict__ U8, const char* __restrict__ W8,
    const float* __restrict__ z, const float* __restrict__ dtp,
    const float* __restrict__ bih, const float* __restrict__ bhh,
    const float* __restrict__ Wdt, const float* __restrict__ bdt,
    float* __restrict__ out, char* __restrict__ zn8,
    unsigned short* __restrict__ sbb) {
  __shared__ char lds[114688];  // A 4x16KB + B 4x12KB
  char* ldsA = lds;
  char* ldsB = lds + 65536;
  const int bid = blockIdx.x;
  const int sid = (bid & 7) * 128 + (bid >> 3);  // XCD-bijective (1024 % 8 == 0)
  const int bm = sid >> 4, bn = sid & 15;
  const long arow0 = (long)bm * 256, brow0 = (long)bn * 192;
  constexpr int NT = 32;

  const int t = threadIdx.x, lane = t & 63, wv = t >> 6;
  const int wm = wv >> 2, wn = wv & 3;
  const int rA = lane & 15;
  const int cphys = ((lane >> 4) << 4) ^ (((rA >> 1) & 3) << 4);
  const int t16 = t * 16;
  const bool blo = (t < 256);

  const int sA = t16 ^ (((t16 >> 7) & 3) << 4);
  const int rA0 = sA >> 6, cA0 = sA & 63;
  const char* pAa = U8 + (arow0 + rA0) * (long)K1 + cA0;
  const char* pAb = U8 + (arow0 + rA0 + 128) * (long)K1 + cA0;

  const int Lb0 = blo ? t16 : t16 + 4096;
  const int Lb1 = t16 + 4096;
  const int sB0 = Lb0 ^ (((Lb0 >> 7) & 3) << 4);
  const int sB1 = Lb1 ^ (((Lb1 >> 7) & 3) << 4);
  const char* pBg0 = W8 + (brow0 + (sB0 >> 6)) * (long)K1 + (sB0 & 63);
  const char* pBg1 = W8 + (brow0 + (sB1 >> 6)) * (long)K1 + (sB1 & 63);

  int offA[8], offB[3];
#pragma unroll
  for (int m = 0; m < 8; ++m)
    offA[m] = (wm * 128 + m * 16 + rA) * 64 + cphys;
#pragma unroll
  for (int n = 0; n < 3; ++n)
    offB[n] = (wn * 48 + n * 16 + rA) * 64 + cphys;

#define STAGE_(TT)                                                        \
  do {                                                                    \
    char* ab_ = ldsA + ((TT) & 3) * 16384;                                \
    char* bb_ = ldsB + ((TT) & 3) * 12288;                                \
    async16(pAa + (long)(TT) * 64, ab_ + t16);                            \
    async16(pAb + (long)(TT) * 64, ab_ + 8192 + t16);                     \
    async16(pBg0 + (long)(TT) * 64, bb_ + Lb0);                           \
    if (blo) async16(pBg1 + (long)(TT) * 64, bb_ + Lb1);                  \
  } while (0)
#define WSTEADY_                                                          \
  do {                                                                    \
    if (blo) asm volatile("s_waitcnt vmcnt(8) lgkmcnt(0)" ::: "memory");  \
    else     asm volatile("s_waitcnt vmcnt(6) lgkmcnt(0)" ::: "memory");  \
  } while (0)
#define WTAIL1_                                                           \
  do {                                                                    \
    if (blo) asm volatile("s_waitcnt vmcnt(4) lgkmcnt(0)" ::: "memory");  \
    else     asm volatile("s_waitcnt vmcnt(3) lgkmcnt(0)" ::: "memory");  \
  } while (0)
#define WTAIL0_ asm volatile("s_waitcnt vmcnt(0) lgkmcnt(0)" ::: "memory")
#define WLAST_  asm volatile("s_waitcnt lgkmcnt(0)" ::: "memory")

  i32x4 acc[8][3];
#pragma unroll
  for (int m = 0; m < 8; ++m)
#pragma unroll
    for (int n = 0; n < 3; ++n) acc[m][n] = (i32x4)(0);

  STAGE_(0);
  STAGE_(1);
  STAGE_(2);
  WSTEADY_;
  __builtin_amdgcn_s_barrier();

#pragma unroll 1
  for (int kt = 0; kt < NT; ++kt) {
    const char* Ab_ = ldsA + (kt & 3) * 16384;
    const char* Bb_ = ldsB + (kt & 3) * 12288;
    i32x4 af_[8], bf_[3];
#pragma unroll
    for (int m = 0; m < 8; ++m) af_[m] = *(const i32x4*)(Ab_ + offA[m]);
#pragma unroll
    for (int n = 0; n < 3; ++n) bf_[n] = *(const i32x4*)(Bb_ + offB[n]);
    if (kt < NT - 3) {
      STAGE_(kt + 3);
      WSTEADY_;
    } else if (kt == NT - 3) {
      WTAIL1_;
    } else if (kt == NT - 2) {
      WTAIL0_;
    } else {
      WLAST_;
    }
    __builtin_amdgcn_s_barrier();
    __builtin_amdgcn_sched_barrier(0);
    __builtin_amdgcn_s_setprio(1);
#pragma unroll
    for (int m = 0; m < 8; ++m)
#pragma unroll
      for (int n = 0; n < 3; ++n)
        acc[m][n] = __builtin_amdgcn_mfma_i32_16x16x64_i8(
            af_[m], bf_[n], acc[m][n], 0, 0, 0);
    __builtin_amdgcn_s_setprio(0);
  }
#undef STAGE_
#undef WSTEADY_
#undef WTAIL1_
#undef WTAIL0_
#undef WLAST_

  // ---- epilogue: dequant + LEM elementwise; z_new stored f32 + i8 ----
  const int q4 = (lane >> 4) << 2;
  const int h = bn * 64 + wn * 16 + rA;
  const int rowbase = bm * 256 + wm * 128;
  const float bi0 = bih[h] + bhh[h];
  const float bi1 = bih[HDIM + h] + bhh[HDIM + h];
  const float bi2 = bih[3 * HDIM + h] + bhh[2 * HDIM + h];
  const float wdt0 = Wdt[0], wdt1 = Wdt[1], bdt0 = bdt[0], bdt1 = bdt[1];
#pragma unroll
  for (int m = 0; m < 8; ++m) {
#pragma unroll
    for (int j = 0; j < 4; ++j) {
      const int b = rowbase + m * 16 + q4 + j;
      const long idx = (long)b * HDIM + h;
      const float dv = dtp[b];
      const float s1 = sigmoidf_(dv * wdt0 + bdt0);
      const float s2 = sigmoidf_(dv * wdt1 + bdt1);
      const float g0 = (float)acc[m][0][j] * SXW + bi0;
      const float g1 = (float)acc[m][1][j] * SXW + bi1;
      const float g2 = (float)acc[m][2][j] * SXW + bi2;
      const float sbar = s1 * sigmoidf_(g0);
      const float s = s2 * sigmoidf_(g1);
      const float zt = tanhf_(g2);
      const float znew = (1.0f - s) * z[idx] + s * zt;
      out[(long)BATCH * HDIM + idx] = znew;  // z_new output (f32)
      int qz = __float2int_rn(fminf(fmaxf(znew * QXS, -127.f), 127.f));
      zn8[idx] = (char)qz;                    // i8 A-half for phase 2
      sbb[idx] = f2bf(sbar);
    }
  }
}

// ===== gemm2: i8 core (256x128 tile, 16 MFMA/barrier), NT=32, KSPLIT=16 =====
// A = [z_new | x]: K-tiles 0-15 from Zn8 (stride 1024), 16-31 from U8's
// x-half (stride 2048). B = Wz8 (128x64B=8KB/tile, 1 uniform load/thread).
// Same 4-buffer distance-3 ring; stage = 3 loads -> vmcnt 6/3/0.
__global__ __launch_bounds__(512, 2) void k_gemm2(
    const char* __restrict__ Zn8, const char* __restrict__ U8,
    const char* __restrict__ Wz8, const unsigned short* __restrict__ sbb,
    const float* __restrict__ yin, const float* __restrict__ bz,
    float* __restrict__ out) {
  __shared__ char lds[98304];  // A 4x16KB + B 4x8KB
  char* ldsA = lds;
  char* ldsB = lds + 65536;
  const int bid = blockIdx.x;
  const int sid = (bid & 7) * 64 + (bid >> 3);  // 512 % 8 == 0
  const int bm = sid >> 3, bn = sid & 7;
  const long arow0 = (long)bm * 256, brow0 = (long)bn * 128;
  constexpr int NT = 32, KSPLIT = 16;

  const int t = threadIdx.x, lane = t & 63, wv = t >> 6;
  const int wm = wv >> 2, wn = wv & 3;
  const int rA = lane & 15;
  const int cphys = ((lane >> 4) << 4) ^ (((rA >> 1) & 3) << 4);
  const int t16 = t * 16;

  const int sA = t16 ^ (((t16 >> 7) & 3) << 4);
  const int rA0 = sA >> 6, cA0 = sA & 63;
  const char* pZa = Zn8 + (arow0 + rA0) * (long)HDIM + cA0;
  const char* pZb = Zn8 + (arow0 + rA0 + 128) * (long)HDIM + cA0;
  const char* pXa = U8 + (arow0 + rA0) * (long)K1 + cA0;
  const char* pXb = U8 + (arow0 + rA0 + 128) * (long)K1 + cA0;

  const int sB0 = t16 ^ (((t16 >> 7) & 3) << 4);
  const char* pBg0 = Wz8 + (brow0 + (sB0 >> 6)) * (long)K1 + (sB0 & 63);

  int offA[8], offB[2];
#pragma unroll
  for (int m = 0; m < 8; ++m)
    offA[m] = (wm * 128 + m * 16 + rA) * 64 + cphys;
#pragma unroll
  for (int n = 0; n < 2; ++n)
    offB[n] = (wn * 32 + n * 16 + rA) * 64 + cphys;

#define STAGE2_(TT)                                                       \
  do {                                                                    \
    char* ab_ = ldsA + ((TT) & 3) * 16384;                                \
    char* bb_ = ldsB + ((TT) & 3) * 8192;                                 \
    if ((TT) < KSPLIT) {                                                  \
      async16(pZa + (long)(TT) * 64, ab_ + t16);                          \
      async16(pZb + (long)(TT) * 64, ab_ + 8192 + t16);                   \
    } else {                                                              \
      async16(pXa + (long)((TT) - KSPLIT) * 64, ab_ + t16);               \
      async16(pXb + (long)((TT) - KSPLIT) * 64, ab_ + 8192 + t16);        \
    }                                                                     \
    async16(pBg0 + (long)(TT) * 64, bb_ + t16);                           \
  } while (0)
#define W2S_ asm volatile("s_waitcnt vmcnt(6) lgkmcnt(0)" ::: "memory")
#define W2A_ asm volatile("s_waitcnt vmcnt(3) lgkmcnt(0)" ::: "memory")
#define W2B_ asm volatile("s_waitcnt vmcnt(0) lgkmcnt(0)" ::: "memory")
#define W2C_ asm volatile("s_waitcnt lgkmcnt(0)" ::: "memory")

  i32x4 acc[8][2];
#pragma unroll
  for (int m = 0; m < 8; ++m)
#pragma unroll
    for (int n = 0; n < 2; ++n) acc[m][n] = (i32x4)(0);

  STAGE2_(0);
  STAGE2_(1);
  STAGE2_(2);
  W2S_;
  __builtin_amdgcn_s_barrier();

#pragma unroll 1
  for (int kt = 0; kt < NT; ++kt) {
    const char* Ab_ = ldsA + (kt & 3) * 16384;
    const char* Bb_ = ldsB + (kt & 3) * 8192;
    i32x4 af_[8], bf_[2];
#pragma unroll
    for (int m = 0; m < 8; ++m) af_[m] = *(const i32x4*)(Ab_ + offA[m]);
#pragma unroll
    for (int n = 0; n < 2; ++n) bf_[n] = *(const i32x4*)(Bb_ + offB[n]);
    if (kt < NT - 3) {
      STAGE2_(kt + 3);
      W2S_;
    } else if (kt == NT - 3) {
      W2A_;
    } else if (kt == NT - 2) {
      W2B_;
    } else {
      W2C_;
    }
    __builtin_amdgcn_s_barrier();
    __builtin_amdgcn_sched_barrier(0);
    __builtin_amdgcn_s_setprio(1);
#pragma unroll
    for (int m = 0; m < 8; ++m)
#pragma unroll
      for (int n = 0; n < 2; ++n)
        acc[m][n] = __builtin_amdgcn_mfma_i32_16x16x64_i8(
            af_[m], bf_[n], acc[m][n], 0, 0, 0);
    __builtin_amdgcn_s_setprio(0);
  }
#undef STAGE2_
#undef W2S_
#undef W2A_
#undef W2B_
#undef W2C_

  // ---- epilogue: dequant + y_new ----
  const int q4 = (lane >> 4) << 2;
  const int rowbase = bm * 256 + wm * 128;
#pragma unroll
  for (int n = 0; n < 2; ++n) {
    const int hc = bn * 128 + wn * 32 + n * 16 + rA;
    const float bzv = bz[hc];
#pragma unroll
    for (int m = 0; m < 8; ++m) {
#pragma unroll
      for (int j = 0; j < 4; ++j) {
        const int b = rowbase + m * 16 + q4 + j;
        const long idx = (long)b * HDIM + hc;
        const float tv = tanhf_((float)acc[m][n][j] * SXW + bzv);
        const float sb = bf2f(sbb[idx]);
        out[idx] = (1.0f - sb) * yin[idx] + sb * tv;  // y_new
      }
    }
  }
}

extern "C" void kernel_launch(void* const* d_in, const int* in_sizes, int n_in,
                              void* d_out, int out_size, void* d_ws, size_t ws_size,
                              hipStream_t stream) {
  const float* x   = (const float*)d_in[0];
  const float* y   = (const float*)d_in[1];
  const float* z   = (const float*)d_in[2];
  const float* dtp = (const float*)d_in[3];
  const float* Wih = (const float*)d_in[4];
  const float* bih = (const float*)d_in[5];
  const float* Whh = (const float*)d_in[6];
  const float* bhh = (const float*)d_in[7];
  const float* Wz  = (const float*)d_in[8];
  const float* bz  = (const float*)d_in[9];
  const float* Wdt = (const float*)d_in[10];
  const float* bdt = (const float*)d_in[11];

  char* ws = (char*)d_ws;
  char*           U8  = ws;                                  // 33,554,432 B
  char*           W8  = ws + 33554432;                       //  6,291,456 B
  char*           Wz8 = ws + 39845888;                       //  2,097,152 B
  char*           Zn8 = ws + 41943040;                       // 16,777,216 B
  unsigned short* Sbb = (unsigned short*)(ws + 58720256);    // 33,554,432 B -> 92,274,688 B
  float* out = (float*)d_out;

  k_conv<<<2048, 256, 0, stream>>>(x, y, Wih, Whh, Wz, U8, W8, Wz8);
  k_gemm1<<<1024, 512, 0, stream>>>(U8, W8, z, dtp, bih, bhh, Wdt, bdt, out, Zn8, Sbb);
  k_gemm2<<<512, 512, 0, stream>>>(Zn8, U8, Wz8, Sbb, y, bz, out);
}